// Round 7
// baseline (1205.588 us; speedup 1.0000x reference)
//
#include <hip/hip_runtime.h>
#include <hip/hip_fp16.h>

#define BB 4
#define HH 240
#define WW 1216
#define NIMG (HH * WW)
#define NPIX (BB * NIMG)          // 1,167,360
#define GRID_PRE (NPIX / 256)     // 4560
#define GRID_PROP (NPIX / 1024)   // 1140 (4 pixels per thread)

// padded feat layout: image pixel (y,x) lives at (y+2, x+2); 5x5 window of
// pixel (y,x) starts at padded (y, x). Pad cells only ever get weight 0.
#define HHP (HH + 4)              // 244
#define WWP (WW + 4)              // 1220
#define PIMG (HHP * WWP)

// confidence padded with 2 zero rows/cols each side (+1 slack bottom/right)
#define CHP 245
#define CWP 1221
#define CIMG (CHP * CWP)

#define OVF_CAP 32000

typedef __attribute__((ext_vector_type(2))) float float2v;
typedef __attribute__((ext_vector_type(4))) unsigned uint4v;

struct OvfEntry {                 // exception pixel: full 9-tap data
    int p;
    int base[9];                  // padded-layout corner base indices
    float w[36];                  // 4 premultiplied fp32 weights per tap
};

__device__ __forceinline__ unsigned f2h(float f) {
    union { _Float16 h; unsigned short u; } cv;
    cv.h = (_Float16)f;
    return (unsigned)cv.u;
}
__device__ __forceinline__ float h2f(unsigned u) {
    union { unsigned short u; _Float16 h; } cv;
    cv.u = (unsigned short)(u & 0xffffu);
    return (float)cv.h;
}

// ---------------------------------------------------------------------------
__global__ __launch_bounds__(256) void k_permute(const float* __restrict__ W_oa,
                                                 float* __restrict__ Wre) {
    for (int i = threadIdx.x; i < 24 * 8 * 9; i += 256) {
        int o = i / 72;
        int r = i - o * 72;
        int c = r / 9;
        int t = r - c * 9;
        Wre[(c * 9 + t) * 24 + o] = W_oa[i];
    }
}

__global__ __launch_bounds__(256) void k_padconf(const float* __restrict__ conf,
                                                 float* __restrict__ cpad) {
    int i = blockIdx.x * 256 + threadIdx.x;
    if (i >= BB * CIMG) return;
    int xp = i % CWP;
    int yp = (i / CWP) % CHP;
    int b = i / CIMG;
    float v = 0.f;
    int y = yp - 2, x = xp - 2;
    if (y >= 0 && y < HH && x >= 0 && x < WW) v = conf[b * NIMG + y * WW + x];
    cpad[i] = v;
}

__device__ __forceinline__ float fast_tanh(float x) {
    float xc = fminf(fmaxf(x, -15.f), 15.f);
    float e = __expf(2.f * xc);
    return 1.f - 2.f * __builtin_amdgcn_rcpf(e + 1.f);
}

// conv helper: 8->24ch 3x3, packed-f32 accumulators, clustered loads for MLP.
template <bool GUARD>
__device__ __forceinline__ void conv_accum(const float* __restrict__ gb,
                                           int y, int x,
                                           const float* __restrict__ Wre,
                                           float2v* acc2) {
#pragma unroll 2
    for (int c = 0; c < 8; c++) {
        const float* gc = gb + c * NIMG;
        float gv[9];
#pragma unroll
        for (int t = 0; t < 9; t++) {
            int dy = t / 3 - 1;
            int dx = t - (t / 3) * 3 - 1;
            if (GUARD) {
                int yy = y + dy, xx = x + dx;
                gv[t] = (yy >= 0 && yy < HH && xx >= 0 && xx < WW)
                            ? gc[yy * WW + xx] : 0.f;
            } else {
                gv[t] = gc[(y + dy) * WW + (x + dx)];
            }
        }
#pragma unroll
        for (int t = 0; t < 9; t++) {
            const float2v* w2 = (const float2v*)(Wre + (c * 9 + t) * 24);
            float2v g2 = {gv[t], gv[t]};
#pragma unroll
            for (int o = 0; o < 12; o++)
                acc2[o] = __builtin_elementwise_fma(g2, w2[o], acc2[o]);
        }
    }
}

// ---------------------------------------------------------------------------
// Precompute: conv head -> affinities -> dense 5x5 window weights built in
// REGISTERS via separable outer-product accumulation (no LDS, static idx).
// Wt layout: AoS per quad: Wt[q*52 + j*4 + (p&3)], j<13 packed fp16 pairs.
// Flag (plane 12 high half): bit15 = fixed pixel; bits[14:0] = ovf idx + 1.
// Fixed pixels are pre-written into BOTH ping-pong buffers (constant value).
// ---------------------------------------------------------------------------
__global__ __launch_bounds__(256) void k_precompute(
    const float* __restrict__ guid, const float* __restrict__ cpad,
    const float* __restrict__ feat_init, const float* __restrict__ feat_fix,
    const float* __restrict__ Wre, const float* __restrict__ b_oa,
    const float* __restrict__ aff_scale,
    float* __restrict__ F0, float* __restrict__ F1,
    unsigned* __restrict__ Wt,
    OvfEntry* __restrict__ ovf, int* __restrict__ ovf_cnt) {
    int p = blockIdx.x * 256 + threadIdx.x;
    int x = p % WW;
    int y = (p / WW) % HH;
    int b = p / NIMG;

    float ff = feat_fix[p];
    bool isfix = (ff > 0.f);
    unsigned fixbit = isfix ? 0x8000u : 0u;

    // ---- 3x3 conv, 8 in-ch -> 24 out-ch, zero pad (packed f32) ----
    float2v acc2[12];
    const float2v* b2 = (const float2v*)b_oa;
#pragma unroll
    for (int o = 0; o < 12; o++) acc2[o] = b2[o];

    const float* gb = guid + (size_t)b * 8 * NIMG;
    bool interior = (y >= 1) && (y <= HH - 2) && (x >= 1) && (x <= WW - 2);
    if (interior) conv_accum<false>(gb, y, x, Wre, acc2);
    else          conv_accum<true>(gb, y, x, Wre, acc2);

    float acc[24];
#pragma unroll
    for (int o = 0; o < 24; o++)
        acc[o] = (o & 1) ? acc2[o >> 1].y : acc2[o >> 1].x;

    // ---- TGASS affinity + confidence modulation ----
    float inv_ascale = __builtin_amdgcn_rcpf(aff_scale[0] + 1e-8f);
    const float* cb = cpad + (size_t)b * CIMG;
    float aff[8], ofy[8], ofx[8];
    float asum = 0.f;
#pragma unroll
    for (int k = 0; k < 8; k++) {
        float dy = acc[k];
        float dx = acc[8 + k];
        ofy[k] = dy;
        ofx[k] = dx;
        float a = fast_tanh(acc[16 + k]) * inv_ascale;
        float ys = dy + (float)y;
        float xs = dx + (float)x;
        float y0f = floorf(ys), x0f = floorf(xs);
        float wy = ys - y0f, wx = xs - x0f;
        int ya = (int)(fminf(fmaxf(y0f, -2.f), 241.f)) + 2;
        int yb = (int)(fminf(fmaxf(y0f + 1.f, -2.f), 241.f)) + 2;
        int xa = (int)(fminf(fmaxf(x0f, -2.f), 1217.f)) + 2;
        int xb = (int)(fminf(fmaxf(x0f + 1.f, -2.f), 1217.f)) + 2;
        float v00 = cb[ya * CWP + xa];
        float v01 = cb[ya * CWP + xb];
        float v10 = cb[yb * CWP + xa];
        float v11 = cb[yb * CWP + xb];
        float v = (v00 * (1.f - wx) + v01 * wx) * (1.f - wy)
                + (v10 * (1.f - wx) + v11 * wx) * wy;
        a *= v;
        aff[k] = a;
        asum += fabsf(a);
    }

    float s = fmaxf(asum + 1e-4f, 1.0f);
    float inv = __builtin_amdgcn_rcpf(s);
    float tot = 0.f;
#pragma unroll
    for (int k = 0; k < 8; k++) {
        aff[k] *= inv;
        tot += aff[k];
    }
    float aref = 1.0f - tot;

    // ---- register 5x5 window: separable outer-product accumulation ----
    float w[25];
#pragma unroll
    for (int i = 0; i < 25; i++) w[i] = 0.f;
    bool fits = true;
#pragma unroll
    for (int kk = 0; kk < 9; kk++) {
        float a, dy, dx;
        if (kk < 4)       { a = aff[kk];     dy = ofy[kk];     dx = ofx[kk]; }
        else if (kk == 4) { a = aref;        dy = 0.f;         dx = 0.f; }
        else              { a = aff[kk - 1]; dy = ofy[kk - 1]; dx = ofx[kk - 1]; }
        const int kh = kk / 3 - 1;
        const int kw = kk - (kk / 3) * 3 - 1;
        float fly = floorf(dy), flx = floorf(dx);
        fits = fits && (fly >= -1.f) && (fly <= 0.f)
                    && (flx >= -1.f) && (flx <= 0.f);
        float wy = dy - fly, wx = dx - flx;
        float byf = fly + 1.f, bxf = flx + 1.f;     // in {0,1} on fast path
        int y0 = y + kh + (int)fly;
        int x0 = x + kw + (int)flx;
        float cy0 = (y0 >= 0 && y0 <= HH - 1) ? (1.f - wy) : 0.f;
        float cy1 = (y0 + 1 >= 0 && y0 + 1 <= HH - 1) ? wy : 0.f;
        float cx0 = (x0 >= 0 && x0 <= WW - 1) ? (1.f - wx) : 0.f;
        float cx1 = (x0 + 1 >= 0 && x0 + 1 <= WW - 1) ? wx : 0.f;
        float cya0 = cy0 * a, cya1 = cy1 * a;
        float ry0 = cya0 - byf * cya0;
        float ry1 = fmaf(byf, cya0, cya1 - byf * cya1);
        float ry2 = byf * cya1;
        float rx0 = cx0 - bxf * cx0;
        float rx1 = fmaf(bxf, cx0, cx1 - bxf * cx1);
        float rx2 = bxf * cx1;
        const int base = (kh + 1) * 5 + (kw + 1);   // compile-time
        w[base + 0]  = fmaf(ry0, rx0, w[base + 0]);
        w[base + 1]  = fmaf(ry0, rx1, w[base + 1]);
        w[base + 2]  = fmaf(ry0, rx2, w[base + 2]);
        w[base + 5]  = fmaf(ry1, rx0, w[base + 5]);
        w[base + 6]  = fmaf(ry1, rx1, w[base + 6]);
        w[base + 7]  = fmaf(ry1, rx2, w[base + 7]);
        w[base + 10] = fmaf(ry2, rx0, w[base + 10]);
        w[base + 11] = fmaf(ry2, rx1, w[base + 11]);
        w[base + 12] = fmaf(ry2, rx2, w[base + 12]);
    }

    unsigned* wdst = Wt + (size_t)(p >> 2) * 52 + (p & 3);
    float yf = (float)y, xf = (float)x;
    if (fits) {
#pragma unroll
        for (int j = 0; j < 13; j++) {
            unsigned lo = f2h(w[2 * j]);
            unsigned hi = (j < 12) ? f2h(w[2 * j + 1]) : fixbit;
            __builtin_nontemporal_store(lo | (hi << 16), wdst + j * 4);
        }
    } else {
        int slot = atomicAdd(ovf_cnt, 1);
        unsigned fl = (slot < OVF_CAP) ? (unsigned)(slot + 1) : 0x7fffu;
        if (slot < OVF_CAP) {
            OvfEntry* e = &ovf[slot];
            e->p = p;
#pragma unroll
            for (int kk = 0; kk < 9; kk++) {
                float a, dy, dx;
                if (kk < 4)       { a = aff[kk];     dy = ofy[kk];     dx = ofx[kk]; }
                else if (kk == 4) { a = aref;        dy = 0.f;         dx = 0.f; }
                else              { a = aff[kk - 1]; dy = ofy[kk - 1]; dx = ofx[kk - 1]; }
                float ys = yf + (float)(kk / 3 - 1) + dy;
                float xs = xf + (float)(kk - (kk / 3) * 3 - 1) + dx;
                float y0f = floorf(ys), x0f = floorf(xs);
                float wy = ys - y0f, wx = xs - x0f;
                float y0c = fminf(fmaxf(y0f, -2.f), (float)HH);
                float x0c = fminf(fmaxf(x0f, -2.f), (float)WW);
                int y0 = (int)y0c, x0 = (int)x0c;
                int by = min(max(y0, 0), HH - 2);
                int bx = min(max(x0, 0), WW - 2);
                float cy0 = 0.f, cy1 = 0.f;
                if (y0 >= 0 && y0 <= HH - 1) { if (y0 == by) cy0 = 1.f - wy; else cy1 = 1.f - wy; }
                if (y0 + 1 >= 0 && y0 + 1 <= HH - 1) { if (y0 + 1 == by) cy0 = wy; else cy1 = wy; }
                float cx0 = 0.f, cx1 = 0.f;
                if (x0 >= 0 && x0 <= WW - 1) { if (x0 == bx) cx0 = 1.f - wx; else cx1 = 1.f - wx; }
                if (x0 + 1 >= 0 && x0 + 1 <= WW - 1) { if (x0 + 1 == bx) cx0 = wx; else cx1 = wx; }
                e->base[kk] = (b * HHP + by + 2) * WWP + bx + 2;
                e->w[kk * 4 + 0] = cy0 * cx0 * a;
                e->w[kk * 4 + 1] = cy0 * cx1 * a;
                e->w[kk * 4 + 2] = cy1 * cx0 * a;
                e->w[kk * 4 + 3] = cy1 * cx1 * a;
            }
        }
#pragma unroll
        for (int j = 0; j < 13; j++)
            __builtin_nontemporal_store((j == 12) ? ((fl | fixbit) << 16) : 0u,
                                        wdst + j * 4);
    }

    // ---- initial feat (padded layout); fixed px into BOTH buffers ----
    int pp = (b * HHP + y + 2) * WWP + x + 2;
    F0[pp] = isfix ? ff : feat_init[p];
    if (isfix) F1[pp] = ff;
}

// general 9-tap (exception) raw stencil value from padded Fin
__device__ __forceinline__ float general9(const OvfEntry* __restrict__ e,
                                          const float* __restrict__ Fin) {
    float s = 0.f;
#pragma unroll
    for (int kk = 0; kk < 9; kk++) {
        int base = e->base[kk];
        s = fmaf(Fin[base],           e->w[kk * 4 + 0], s);
        s = fmaf(Fin[base + 1],       e->w[kk * 4 + 1], s);
        s = fmaf(Fin[base + WWP],     e->w[kk * 4 + 2], s);
        s = fmaf(Fin[base + WWP + 1], e->w[kk * 4 + 3], s);
    }
    return s;
}

// ---------------------------------------------------------------------------
// One propagation step: dense 5x5 stencil, 4 pixels per thread.
// Wt is AoS per quad (208B contiguous, nontemporal). No feat_fix stream:
// fixed pixels (flag bit15) are skipped on intermediate stores (their value
// is pre-baked in both buffers) and stored normally on the last step.
// ---------------------------------------------------------------------------
__global__ __launch_bounds__(256) void k_prop(
    const float* __restrict__ Fin, const unsigned* __restrict__ Wt,
    const float* __restrict__ feat_fix, const OvfEntry* __restrict__ ovf,
    const int* __restrict__ ovf_cnt, float* __restrict__ Fout, int last) {
    if (blockIdx.x == GRID_PROP) {
        // -------- exception pixels: general 9-tap from global Fin ---------
        int cnt = *ovf_cnt;
        if (cnt > OVF_CAP) cnt = OVF_CAP;
        for (int i = threadIdx.x; i < cnt; i += 256) {
            const OvfEntry* e = &ovf[i];
            float s = general9(e, Fin);
            int p = e->p;
            if (last) {
                Fout[p] = s;
            } else {
                float ff = feat_fix[p];
                int xx = p % WW;
                int yy = (p / WW) % HH;
                int bb = p / NIMG;
                Fout[(bb * HHP + yy + 2) * WWP + xx + 2] = (ff > 0.f) ? ff : s;
            }
        }
        return;
    }

    int q = blockIdx.x * 256 + threadIdx.x;
    int p = q * 4;                          // quad (p..p+3), same row
    int x = p % WW;
    int y = (p / WW) % HH;
    int b = p / NIMG;
    const float* fb = Fin + (size_t)(b * HHP + y) * WWP + x;

    const uint4v* wq = (const uint4v*)(Wt + (size_t)q * 52);
    uint4v u[13];
#pragma unroll
    for (int j = 0; j < 13; j++)
        u[j] = __builtin_nontemporal_load(wq + j);

    float f[5][8];
#pragma unroll
    for (int r = 0; r < 5; r++) {
        const float* row = fb + r * WWP;
        float4 a0 = *(const float4*)(row);
        float4 a1 = *(const float4*)(row + 4);
        f[r][0] = a0.x; f[r][1] = a0.y; f[r][2] = a0.z; f[r][3] = a0.w;
        f[r][4] = a1.x; f[r][5] = a1.y; f[r][6] = a1.z; f[r][7] = a1.w;
    }

    float s0 = 0.f, s1 = 0.f, s2 = 0.f, s3 = 0.f;
#pragma unroll
    for (int c = 0; c < 25; c++) {
        const int j = c >> 1, r = c / 5, cc = c - r * 5;
        unsigned e0 = (c & 1) ? (u[j].x >> 16) : u[j].x;
        unsigned e1 = (c & 1) ? (u[j].y >> 16) : u[j].y;
        unsigned e2 = (c & 1) ? (u[j].z >> 16) : u[j].z;
        unsigned e3 = (c & 1) ? (u[j].w >> 16) : u[j].w;
        s0 = fmaf(f[r][cc],     h2f(e0), s0);
        s1 = fmaf(f[r][cc + 1], h2f(e1), s1);
        s2 = fmaf(f[r][cc + 2], h2f(e2), s2);
        s3 = fmaf(f[r][cc + 3], h2f(e3), s3);
    }
    unsigned h0 = u[12].x >> 16, h1 = u[12].y >> 16;
    unsigned h2 = u[12].z >> 16, h3 = u[12].w >> 16;

    if (last) {
        // store raw stencil everywhere except ovf pixels (bits[14:0] != 0)
        if (((h0 | h1 | h2 | h3) & 0x7fffu) == 0) {
            float4 o = {s0, s1, s2, s3};
            *(float4*)&Fout[p] = o;
        } else {
            if (!(h0 & 0x7fffu)) Fout[p] = s0;
            if (!(h1 & 0x7fffu)) Fout[p + 1] = s1;
            if (!(h2 & 0x7fffu)) Fout[p + 2] = s2;
            if (!(h3 & 0x7fffu)) Fout[p + 3] = s3;
        }
    } else {
        // skip stores at fixed (bit15) and ovf pixels
        float* po = Fout + (size_t)(b * HHP + y + 2) * WWP + x + 2;
        if ((h0 | h1 | h2 | h3) == 0) {     // po is 8B-aligned
            float2v w01 = {s0, s1};
            float2v w23 = {s2, s3};
            *(float2v*)(po) = w01;
            *(float2v*)(po + 2) = w23;
        } else {
            if (!h0) po[0] = s0;
            if (!h1) po[1] = s1;
            if (!h2) po[2] = s2;
            if (!h3) po[3] = s3;
        }
    }
}

extern "C" void kernel_launch(void* const* d_in, const int* in_sizes, int n_in,
                              void* d_out, int out_size, void* d_ws, size_t ws_size,
                              hipStream_t stream) {
    const float* feat_init  = (const float*)d_in[0];
    const float* guidance   = (const float*)d_in[1];
    const float* confidence = (const float*)d_in[2];
    const float* feat_fix   = (const float*)d_in[3];
    const float* W_oa       = (const float*)d_in[4];
    const float* b_oa       = (const float*)d_in[5];
    const float* aff_scale  = (const float*)d_in[6];

    char* ws = (char*)d_ws;
    size_t off = 0;
    auto carve = [&](size_t bytes) -> char* {
        char* ptr = ws + off;
        off += (bytes + 511) & ~(size_t)511;
        return ptr;
    };
    float*    Wre  = (float*)carve(24 * 8 * 9 * sizeof(float));
    float*    CPAD = (float*)carve((size_t)BB * CIMG * sizeof(float));
    float*    F0   = (float*)carve((size_t)BB * PIMG * sizeof(float));
    float*    F1   = (float*)carve((size_t)BB * PIMG * sizeof(float));
    unsigned* Wt   = (unsigned*)carve((size_t)13 * NPIX * sizeof(unsigned));
    OvfEntry* OVF  = (OvfEntry*)carve((size_t)OVF_CAP * sizeof(OvfEntry));
    int*      CNT  = (int*)carve(sizeof(int));
    (void)ws_size; (void)in_sizes; (void)n_in; (void)out_size;

    hipMemsetAsync(CNT, 0, sizeof(int), stream);

    int gridc = (BB * CIMG + 255) / 256;
    hipLaunchKernelGGL(k_permute, dim3(1), dim3(256), 0, stream, W_oa, Wre);
    hipLaunchKernelGGL(k_padconf, dim3(gridc), dim3(256), 0, stream,
                       confidence, CPAD);
    hipLaunchKernelGGL(k_precompute, dim3(GRID_PRE), dim3(256), 0, stream,
                       guidance, CPAD, feat_init, feat_fix, Wre, b_oa,
                       aff_scale, F0, F1, Wt, OVF, CNT);

    float* bufs[2] = {F0, F1};
    int cur = 0;
    for (int it = 0; it < 18; ++it) {
        int last = (it == 17) ? 1 : 0;
        float* outp = last ? (float*)d_out : bufs[cur ^ 1];
        hipLaunchKernelGGL(k_prop, dim3(GRID_PROP + 1), dim3(256), 0, stream,
                           bufs[cur], Wt, feat_fix, OVF, CNT, outp, last);
        cur ^= 1;
    }
}

// Round 9
// 436.595 us; speedup vs baseline: 2.7613x; 2.7613x over previous
//
#include <hip/hip_runtime.h>
#include <hip/hip_fp16.h>

#define BB 4
#define HH 240
#define WW 1216
#define NIMG (HH * WW)
#define NPIX (BB * NIMG)          // 1,167,360
#define GRID_PRE (NPIX / 256)     // 4560

// padded feat layout: image pixel (y,x) lives at (y+2, x+2); 5x5 window of
// pixel (y,x) starts at padded (y, x). Pad cells only ever get weight 0.
#define HHP (HH + 4)              // 244
#define WWP (WW + 4)              // 1220
#define PIMG (HHP * WWP)

// confidence padded with 2 zero rows/cols each side (+1 slack bottom/right)
#define CHP 245
#define CWP 1221
#define CIMG (CHP * CWP)

#define OVF_CAP 32768

// fused 2-step tiling: B tile 64x16 (256 quads = 1 per thread)
#define TSX 64
#define TSY 16
#define NTX (WW / TSX)            // 19
#define NTY (HH / TSY)            // 15
#define NTILES (NTX * NTY * BB)   // 1140
#define AQC 18                    // A quads per row (x: tilex-4 .. tilex+67)
#define ARY 20                    // A rows (y: tiley-2 .. tiley+17)
#define ASTR 74                   // LDS row stride (74 mod 32 = 10: no repeat)

typedef __attribute__((ext_vector_type(2))) float float2v;

struct OvfEntry {                 // exception pixel: full 9-tap data
    int p;
    int base[9];                  // padded-layout corner base indices
    float w[36];                  // 4 premultiplied fp32 weights per tap
};

__device__ __forceinline__ unsigned f2h(float f) {
    union { _Float16 h; unsigned short u; } cv;
    cv.h = (_Float16)f;
    return (unsigned)cv.u;
}
__device__ __forceinline__ float h2f(unsigned u) {
    union { unsigned short u; _Float16 h; } cv;
    cv.u = (unsigned short)(u & 0xffffu);
    return (float)cv.h;
}

// ---------------------------------------------------------------------------
__global__ __launch_bounds__(256) void k_permute(const float* __restrict__ W_oa,
                                                 float* __restrict__ Wre) {
    for (int i = threadIdx.x; i < 24 * 8 * 9; i += 256) {
        int o = i / 72;
        int r = i - o * 72;
        int c = r / 9;
        int t = r - c * 9;
        Wre[(c * 9 + t) * 24 + o] = W_oa[i];
    }
}

__global__ __launch_bounds__(256) void k_padconf(const float* __restrict__ conf,
                                                 float* __restrict__ cpad) {
    int i = blockIdx.x * 256 + threadIdx.x;
    if (i >= BB * CIMG) return;
    int xp = i % CWP;
    int yp = (i / CWP) % CHP;
    int b = i / CIMG;
    float v = 0.f;
    int y = yp - 2, x = xp - 2;
    if (y >= 0 && y < HH && x >= 0 && x < WW) v = conf[b * NIMG + y * WW + x];
    cpad[i] = v;
}

__device__ __forceinline__ float fast_tanh(float x) {
    float xc = fminf(fmaxf(x, -15.f), 15.f);
    float e = __expf(2.f * xc);
    return 1.f - 2.f * __builtin_amdgcn_rcpf(e + 1.f);
}

// conv helper: 8->24ch 3x3, packed-f32 accumulators, clustered loads for MLP.
template <bool GUARD>
__device__ __forceinline__ void conv_accum(const float* __restrict__ gb,
                                           int y, int x,
                                           const float* __restrict__ Wre,
                                           float2v* acc2) {
#pragma unroll 2
    for (int c = 0; c < 8; c++) {
        const float* gc = gb + c * NIMG;
        float gv[9];
#pragma unroll
        for (int t = 0; t < 9; t++) {
            int dy = t / 3 - 1;
            int dx = t - (t / 3) * 3 - 1;
            if (GUARD) {
                int yy = y + dy, xx = x + dx;
                gv[t] = (yy >= 0 && yy < HH && xx >= 0 && xx < WW)
                            ? gc[yy * WW + xx] : 0.f;
            } else {
                gv[t] = gc[(y + dy) * WW + (x + dx)];
            }
        }
#pragma unroll
        for (int t = 0; t < 9; t++) {
            const float2v* w2 = (const float2v*)(Wre + (c * 9 + t) * 24);
            float2v g2 = {gv[t], gv[t]};
#pragma unroll
            for (int o = 0; o < 12; o++)
                acc2[o] = __builtin_elementwise_fma(g2, w2[o], acc2[o]);
        }
    }
}

// ---------------------------------------------------------------------------
// Precompute: conv head -> affinities -> dense 5x5 window weights in
// registers. Wt layout: PLANAR, Wt[j*NPIX + p] (coalesced). Flag plane 12
// high half: bit15 = fixed pixel, bits[14:0] = ovf idx + 1.
// Fixed pixels are pre-written into BOTH ping-pong buffers.
// ---------------------------------------------------------------------------
__global__ __launch_bounds__(256) void k_precompute(
    const float* __restrict__ guid, const float* __restrict__ cpad,
    const float* __restrict__ feat_init, const float* __restrict__ feat_fix,
    const float* __restrict__ Wre, const float* __restrict__ b_oa,
    const float* __restrict__ aff_scale,
    float* __restrict__ F0, float* __restrict__ F1,
    unsigned* __restrict__ Wt,
    OvfEntry* __restrict__ ovf, int* __restrict__ ovf_cnt) {
    int p = blockIdx.x * 256 + threadIdx.x;
    int x = p % WW;
    int y = (p / WW) % HH;
    int b = p / NIMG;

    float ff = feat_fix[p];
    bool isfix = (ff > 0.f);
    unsigned fixbit = isfix ? 0x8000u : 0u;

    // ---- 3x3 conv, 8 in-ch -> 24 out-ch, zero pad (packed f32) ----
    float2v acc2[12];
    const float2v* b2 = (const float2v*)b_oa;
#pragma unroll
    for (int o = 0; o < 12; o++) acc2[o] = b2[o];

    const float* gb = guid + (size_t)b * 8 * NIMG;
    bool interior = (y >= 1) && (y <= HH - 2) && (x >= 1) && (x <= WW - 2);
    if (interior) conv_accum<false>(gb, y, x, Wre, acc2);
    else          conv_accum<true>(gb, y, x, Wre, acc2);

    float acc[24];
#pragma unroll
    for (int o = 0; o < 24; o++)
        acc[o] = (o & 1) ? acc2[o >> 1].y : acc2[o >> 1].x;

    // ---- TGASS affinity + confidence modulation ----
    float inv_ascale = __builtin_amdgcn_rcpf(aff_scale[0] + 1e-8f);
    const float* cb = cpad + (size_t)b * CIMG;
    float aff[8], ofy[8], ofx[8];
    float asum = 0.f;
#pragma unroll
    for (int k = 0; k < 8; k++) {
        float dy = acc[k];
        float dx = acc[8 + k];
        ofy[k] = dy;
        ofx[k] = dx;
        float a = fast_tanh(acc[16 + k]) * inv_ascale;
        float ys = dy + (float)y;
        float xs = dx + (float)x;
        float y0f = floorf(ys), x0f = floorf(xs);
        float wy = ys - y0f, wx = xs - x0f;
        int ya = (int)(fminf(fmaxf(y0f, -2.f), 241.f)) + 2;
        int yb = (int)(fminf(fmaxf(y0f + 1.f, -2.f), 241.f)) + 2;
        int xa = (int)(fminf(fmaxf(x0f, -2.f), 1217.f)) + 2;
        int xb = (int)(fminf(fmaxf(x0f + 1.f, -2.f), 1217.f)) + 2;
        float v00 = cb[ya * CWP + xa];
        float v01 = cb[ya * CWP + xb];
        float v10 = cb[yb * CWP + xa];
        float v11 = cb[yb * CWP + xb];
        float v = (v00 * (1.f - wx) + v01 * wx) * (1.f - wy)
                + (v10 * (1.f - wx) + v11 * wx) * wy;
        a *= v;
        aff[k] = a;
        asum += fabsf(a);
    }

    float s = fmaxf(asum + 1e-4f, 1.0f);
    float inv = __builtin_amdgcn_rcpf(s);
    float tot = 0.f;
#pragma unroll
    for (int k = 0; k < 8; k++) {
        aff[k] *= inv;
        tot += aff[k];
    }
    float aref = 1.0f - tot;

    // ---- register 5x5 window: separable outer-product accumulation ----
    float w[25];
#pragma unroll
    for (int i = 0; i < 25; i++) w[i] = 0.f;
    bool fits = true;
#pragma unroll
    for (int kk = 0; kk < 9; kk++) {
        float a, dy, dx;
        if (kk < 4)       { a = aff[kk];     dy = ofy[kk];     dx = ofx[kk]; }
        else if (kk == 4) { a = aref;        dy = 0.f;         dx = 0.f; }
        else              { a = aff[kk - 1]; dy = ofy[kk - 1]; dx = ofx[kk - 1]; }
        const int kh = kk / 3 - 1;
        const int kw = kk - (kk / 3) * 3 - 1;
        float fly = floorf(dy), flx = floorf(dx);
        fits = fits && (fly >= -1.f) && (fly <= 0.f)
                    && (flx >= -1.f) && (flx <= 0.f);
        float wy = dy - fly, wx = dx - flx;
        float byf = fly + 1.f, bxf = flx + 1.f;     // in {0,1} on fast path
        int y0 = y + kh + (int)fly;
        int x0 = x + kw + (int)flx;
        float cy0 = (y0 >= 0 && y0 <= HH - 1) ? (1.f - wy) : 0.f;
        float cy1 = (y0 + 1 >= 0 && y0 + 1 <= HH - 1) ? wy : 0.f;
        float cx0 = (x0 >= 0 && x0 <= WW - 1) ? (1.f - wx) : 0.f;
        float cx1 = (x0 + 1 >= 0 && x0 + 1 <= WW - 1) ? wx : 0.f;
        float cya0 = cy0 * a, cya1 = cy1 * a;
        float ry0 = cya0 - byf * cya0;
        float ry1 = fmaf(byf, cya0, cya1 - byf * cya1);
        float ry2 = byf * cya1;
        float rx0 = cx0 - bxf * cx0;
        float rx1 = fmaf(bxf, cx0, cx1 - bxf * cx1);
        float rx2 = bxf * cx1;
        const int base = (kh + 1) * 5 + (kw + 1);   // compile-time
        w[base + 0]  = fmaf(ry0, rx0, w[base + 0]);
        w[base + 1]  = fmaf(ry0, rx1, w[base + 1]);
        w[base + 2]  = fmaf(ry0, rx2, w[base + 2]);
        w[base + 5]  = fmaf(ry1, rx0, w[base + 5]);
        w[base + 6]  = fmaf(ry1, rx1, w[base + 6]);
        w[base + 7]  = fmaf(ry1, rx2, w[base + 7]);
        w[base + 10] = fmaf(ry2, rx0, w[base + 10]);
        w[base + 11] = fmaf(ry2, rx1, w[base + 11]);
        w[base + 12] = fmaf(ry2, rx2, w[base + 12]);
    }

    float yf = (float)y, xf = (float)x;
    if (fits) {
#pragma unroll
        for (int j = 0; j < 13; j++) {
            unsigned lo = f2h(w[2 * j]);
            unsigned hi = (j < 12) ? f2h(w[2 * j + 1]) : fixbit;
            Wt[(size_t)j * NPIX + p] = lo | (hi << 16);
        }
    } else {
        int slot = atomicAdd(ovf_cnt, 1);
        unsigned fl = (slot < OVF_CAP) ? (unsigned)(slot + 1) : 0x7fffu;
        if (slot < OVF_CAP) {
            OvfEntry* e = &ovf[slot];
            e->p = p;
#pragma unroll
            for (int kk = 0; kk < 9; kk++) {
                float a, dy, dx;
                if (kk < 4)       { a = aff[kk];     dy = ofy[kk];     dx = ofx[kk]; }
                else if (kk == 4) { a = aref;        dy = 0.f;         dx = 0.f; }
                else              { a = aff[kk - 1]; dy = ofy[kk - 1]; dx = ofx[kk - 1]; }
                float ys = yf + (float)(kk / 3 - 1) + dy;
                float xs = xf + (float)(kk - (kk / 3) * 3 - 1) + dx;
                float y0f = floorf(ys), x0f = floorf(xs);
                float wy = ys - y0f, wx = xs - x0f;
                float y0c = fminf(fmaxf(y0f, -2.f), (float)HH);
                float x0c = fminf(fmaxf(x0f, -2.f), (float)WW);
                int y0 = (int)y0c, x0 = (int)x0c;
                int by = min(max(y0, 0), HH - 2);
                int bx = min(max(x0, 0), WW - 2);
                float cy0 = 0.f, cy1 = 0.f;
                if (y0 >= 0 && y0 <= HH - 1) { if (y0 == by) cy0 = 1.f - wy; else cy1 = 1.f - wy; }
                if (y0 + 1 >= 0 && y0 + 1 <= HH - 1) { if (y0 + 1 == by) cy0 = wy; else cy1 = wy; }
                float cx0 = 0.f, cx1 = 0.f;
                if (x0 >= 0 && x0 <= WW - 1) { if (x0 == bx) cx0 = 1.f - wx; else cx1 = 1.f - wx; }
                if (x0 + 1 >= 0 && x0 + 1 <= WW - 1) { if (x0 + 1 == bx) cx0 = wx; else cx1 = wx; }
                e->base[kk] = (b * HHP + by + 2) * WWP + bx + 2;
                e->w[kk * 4 + 0] = cy0 * cx0 * a;
                e->w[kk * 4 + 1] = cy0 * cx1 * a;
                e->w[kk * 4 + 2] = cy1 * cx0 * a;
                e->w[kk * 4 + 3] = cy1 * cx1 * a;
            }
        }
#pragma unroll
        for (int j = 0; j < 13; j++)
            Wt[(size_t)j * NPIX + p] = (j == 12) ? ((fl | fixbit) << 16) : 0u;
    }

    // ---- initial feat (padded layout); fixed px into BOTH buffers ----
    int pp = (b * HHP + y + 2) * WWP + x + 2;
    F0[pp] = isfix ? ff : feat_init[p];
    if (isfix) F1[pp] = ff;
}

// general 9-tap (exception) raw stencil value from padded Fin
__device__ __forceinline__ float general9(const OvfEntry* __restrict__ e,
                                          const float* __restrict__ Fin) {
    float s = 0.f;
#pragma unroll
    for (int kk = 0; kk < 9; kk++) {
        int base = e->base[kk];
        s = fmaf(Fin[base],           e->w[kk * 4 + 0], s);
        s = fmaf(Fin[base + 1],       e->w[kk * 4 + 1], s);
        s = fmaf(Fin[base + WWP],     e->w[kk * 4 + 2], s);
        s = fmaf(Fin[base + WWP + 1], e->w[kk * 4 + 3], s);
    }
    return s;
}

// step-A mixed value of the pixel at padded index q (general, exception path)
__device__ float stepA_at(int q, const float* __restrict__ Fin,
                          const unsigned* __restrict__ Wt,
                          const float* __restrict__ feat_fix,
                          const OvfEntry* __restrict__ ovf) {
    int bq = q / PIMG;
    int rem = q - bq * PIMG;
    int yq = rem / WWP - 2;
    int xq = rem % WWP - 2;
    int pq = bq * NIMG + yq * WW + xq;
    float ff = feat_fix[pq];
    if (ff > 0.f) return ff;
    unsigned fl = (Wt[(size_t)12 * NPIX + pq] >> 16) & 0x7fffu;
    if (fl) return general9(&ovf[fl - 1], Fin);
    unsigned u13[13];
#pragma unroll
    for (int j = 0; j < 13; j++) u13[j] = Wt[(size_t)j * NPIX + pq];
    const float* fb = Fin + (q - 2 * WWP - 2);
    float s = 0.f;
#pragma unroll
    for (int c = 0; c < 25; c++) {
        const int j = c >> 1, r = c / 5, cc = c - r * 5;
        unsigned uw = (c & 1) ? (u13[j] >> 16) : u13[j];
        s = fmaf(fb[r * WWP + cc], h2f(uw), s);
    }
    return s;
}

// A-step for one quad (y, xq..xq+3): raw 5x5 stencil + ovf/fix overrides.
// Exports the quad's 13 packed weight words (kept for the B step).
__device__ __forceinline__ void quadA(
    int b, int y, int xq, bool valid,
    const float* __restrict__ Fin, const unsigned* __restrict__ Wt,
    const OvfEntry* __restrict__ ovf,
    uint4* __restrict__ u, float& s0, float& s1, float& s2, float& s3) {
    s0 = s1 = s2 = s3 = 0.f;
    if (!valid) return;
    int p = b * NIMG + y * WW + xq;
#pragma unroll
    for (int j = 0; j < 13; j++)
        u[j] = *(const uint4*)&Wt[(size_t)j * NPIX + p];
    const float* fb = Fin + (size_t)(b * HHP + y) * WWP + xq;
    float f[5][8];
#pragma unroll
    for (int r = 0; r < 5; r++) {
        const float* row = fb + r * WWP;
        float4 a0 = *(const float4*)(row);
        float4 a1 = *(const float4*)(row + 4);
        f[r][0] = a0.x; f[r][1] = a0.y; f[r][2] = a0.z; f[r][3] = a0.w;
        f[r][4] = a1.x; f[r][5] = a1.y; f[r][6] = a1.z; f[r][7] = a1.w;
    }
#pragma unroll
    for (int c = 0; c < 25; c++) {
        const int j = c >> 1, r = c / 5, cc = c - r * 5;
        unsigned e0 = (c & 1) ? (u[j].x >> 16) : u[j].x;
        unsigned e1 = (c & 1) ? (u[j].y >> 16) : u[j].y;
        unsigned e2 = (c & 1) ? (u[j].z >> 16) : u[j].z;
        unsigned e3 = (c & 1) ? (u[j].w >> 16) : u[j].w;
        s0 = fmaf(f[r][cc],     h2f(e0), s0);
        s1 = fmaf(f[r][cc + 1], h2f(e1), s1);
        s2 = fmaf(f[r][cc + 2], h2f(e2), s2);
        s3 = fmaf(f[r][cc + 3], h2f(e3), s3);
    }
    unsigned h0 = u[12].x >> 16, h1 = u[12].y >> 16;
    unsigned h2 = u[12].z >> 16, h3 = u[12].w >> 16;
    if ((h0 | h1 | h2 | h3) != 0) {         // rare: ovf / fixed overrides
        if (h0 & 0x7fffu) s0 = general9(&ovf[(h0 & 0x7fffu) - 1], Fin);
        if (h1 & 0x7fffu) s1 = general9(&ovf[(h1 & 0x7fffu) - 1], Fin);
        if (h2 & 0x7fffu) s2 = general9(&ovf[(h2 & 0x7fffu) - 1], Fin);
        if (h3 & 0x7fffu) s3 = general9(&ovf[(h3 & 0x7fffu) - 1], Fin);
        if (h0 & 0x8000u) s0 = fb[2 * WWP + 2];   // fixed: Fin value == ff
        if (h1 & 0x8000u) s1 = fb[2 * WWP + 3];
        if (h2 & 0x8000u) s2 = fb[2 * WWP + 4];
        if (h3 & 0x8000u) s3 = fb[2 * WWP + 5];
    }
}

// ---------------------------------------------------------------------------
// Fused 2-step propagation. Each thread owns one B quad (64x16 tile, 256
// quads): computes step-A for its own quad KEEPING weights in registers
// (step-B re-reads zero table bytes), helps with the A halo (104 border
// quads), barrier, then computes step-B from LDS A-values + kept weights.
// ---------------------------------------------------------------------------
__global__ __launch_bounds__(256) void k_prop2(
    const float* __restrict__ Fin, const unsigned* __restrict__ Wt,
    const float* __restrict__ feat_fix, const OvfEntry* __restrict__ ovf,
    const int* __restrict__ ovf_cnt, float* __restrict__ Fout, int last) {
    __shared__ float As[ARY * ASTR];
    const int tid = threadIdx.x;
    const int blk = blockIdx.x;

    if (blk == NTILES) {
        // -------- exception pixels: general 2-step from global Fin --------
        int cnt = *ovf_cnt;
        if (cnt > OVF_CAP) cnt = OVF_CAP;
        for (int i = tid; i < cnt; i += 256) {
            const OvfEntry* e = &ovf[i];
            float sB = 0.f;
#pragma unroll 1
            for (int kk = 0; kk < 9; kk++) {
                int base = e->base[kk];
                sB = fmaf(stepA_at(base,           Fin, Wt, feat_fix, ovf), e->w[kk * 4 + 0], sB);
                sB = fmaf(stepA_at(base + 1,       Fin, Wt, feat_fix, ovf), e->w[kk * 4 + 1], sB);
                sB = fmaf(stepA_at(base + WWP,     Fin, Wt, feat_fix, ovf), e->w[kk * 4 + 2], sB);
                sB = fmaf(stepA_at(base + WWP + 1, Fin, Wt, feat_fix, ovf), e->w[kk * 4 + 3], sB);
            }
            int p = e->p;
            if (last) {
                Fout[p] = sB;
            } else {
                float ff = feat_fix[p];
                int xx = p % WW;
                int yy = (p / WW) % HH;
                int bb = p / NIMG;
                Fout[(bb * HHP + yy + 2) * WWP + xx + 2] = (ff > 0.f) ? ff : sB;
            }
        }
        return;
    }

    const int b = blk / (NTX * NTY);
    const int tr = blk - b * (NTX * NTY);
    const int tiley = (tr / NTX) * TSY;
    const int tilex = (tr - (tr / NTX) * NTX) * TSX;
    const int qy = tid >> 4;                // 0..15
    const int qxl = tid & 15;               // 0..15

    // ---- A halo: 104 border quads (rows 0,1,18,19 full; cols 0,17 sides) --
    if (tid < 104) {
        int ar, ac;
        if (tid < 36)      { ar = tid / 18;             ac = tid % 18; }
        else if (tid < 72) { ar = 18 + (tid - 36) / 18; ac = (tid - 36) % 18; }
        else               { int i2 = tid - 72; ar = 2 + (i2 >> 1); ac = (i2 & 1) * 17; }
        int ya = tiley - 2 + ar;
        int xa = tilex - 4 + ac * 4;
        bool valid = (ya >= 0) && (ya < HH) && (xa >= 0) && (xa < WW);
        uint4 ub[13];
        float t0, t1, t2, t3;
        quadA(b, ya, xa, valid, Fin, Wt, ovf, ub, t0, t1, t2, t3);
        float* ap = As + ar * ASTR + ac * 4;
        float2v v01 = {t0, t1};
        float2v v23 = {t2, t3};
        *(float2v*)(ap) = v01;
        *(float2v*)(ap + 2) = v23;
    }

    // ---- A own quad (keep weights u for step B) ----
    uint4 u[13];
    float a0, a1, a2, a3;
    {
        int ar = qy + 2, ac = qxl + 1;
        int ya = tiley + qy;
        int xa = tilex + qxl * 4;
        quadA(b, ya, xa, true, Fin, Wt, ovf, u, a0, a1, a2, a3);
        float* ap = As + ar * ASTR + ac * 4;
        float2v v01 = {a0, a1};
        float2v v23 = {a2, a3};
        *(float2v*)(ap) = v01;
        *(float2v*)(ap + 2) = v23;
    }
    __syncthreads();

    // ---- B step: window from LDS, weights from kept registers ----
    float f[5][8];
    const float* As0 = As + qy * ASTR + qxl * 4 + 2;
#pragma unroll
    for (int r = 0; r < 5; r++) {
        const float* row = As0 + r * ASTR;
        float2v c0 = *(const float2v*)(row);
        float2v c1 = *(const float2v*)(row + 2);
        float2v c2 = *(const float2v*)(row + 4);
        float2v c3 = *(const float2v*)(row + 6);
        f[r][0] = c0.x; f[r][1] = c0.y; f[r][2] = c1.x; f[r][3] = c1.y;
        f[r][4] = c2.x; f[r][5] = c2.y; f[r][6] = c3.x; f[r][7] = c3.y;
    }

    float s0 = 0.f, s1 = 0.f, s2 = 0.f, s3 = 0.f;
#pragma unroll
    for (int c = 0; c < 25; c++) {
        const int j = c >> 1, r = c / 5, cc = c - r * 5;
        unsigned e0 = (c & 1) ? (u[j].x >> 16) : u[j].x;
        unsigned e1 = (c & 1) ? (u[j].y >> 16) : u[j].y;
        unsigned e2 = (c & 1) ? (u[j].z >> 16) : u[j].z;
        unsigned e3 = (c & 1) ? (u[j].w >> 16) : u[j].w;
        s0 = fmaf(f[r][cc],     h2f(e0), s0);
        s1 = fmaf(f[r][cc + 1], h2f(e1), s1);
        s2 = fmaf(f[r][cc + 2], h2f(e2), s2);
        s3 = fmaf(f[r][cc + 3], h2f(e3), s3);
    }
    unsigned h0 = u[12].x >> 16, h1 = u[12].y >> 16;
    unsigned h2 = u[12].z >> 16, h3 = u[12].w >> 16;

    const int yb = tiley + qy;
    const int xb = tilex + qxl * 4;
    if (last) {
        // store raw everywhere except ovf pixels (exception block writes)
        int p = b * NIMG + yb * WW + xb;
        if (((h0 | h1 | h2 | h3) & 0x7fffu) == 0) {
            float4 o = {s0, s1, s2, s3};
            *(float4*)&Fout[p] = o;
        } else {
            if (!(h0 & 0x7fffu)) Fout[p] = s0;
            if (!(h1 & 0x7fffu)) Fout[p + 1] = s1;
            if (!(h2 & 0x7fffu)) Fout[p + 2] = s2;
            if (!(h3 & 0x7fffu)) Fout[p + 3] = s3;
        }
    } else {
        // skip stores at fixed (bit15, value pre-baked) and ovf pixels
        float* po = Fout + (size_t)(b * HHP + yb + 2) * WWP + xb + 2;
        if ((h0 | h1 | h2 | h3) == 0) {
            float2v w01 = {s0, s1};
            float2v w23 = {s2, s3};
            *(float2v*)(po) = w01;
            *(float2v*)(po + 2) = w23;
        } else {
            if (!h0) po[0] = s0;
            if (!h1) po[1] = s1;
            if (!h2) po[2] = s2;
            if (!h3) po[3] = s3;
        }
    }
}

extern "C" void kernel_launch(void* const* d_in, const int* in_sizes, int n_in,
                              void* d_out, int out_size, void* d_ws, size_t ws_size,
                              hipStream_t stream) {
    const float* feat_init  = (const float*)d_in[0];
    const float* guidance   = (const float*)d_in[1];
    const float* confidence = (const float*)d_in[2];
    const float* feat_fix   = (const float*)d_in[3];
    const float* W_oa       = (const float*)d_in[4];
    const float* b_oa       = (const float*)d_in[5];
    const float* aff_scale  = (const float*)d_in[6];

    char* ws = (char*)d_ws;
    size_t off = 0;
    auto carve = [&](size_t bytes) -> char* {
        char* ptr = ws + off;
        off += (bytes + 511) & ~(size_t)511;
        return ptr;
    };
    float*    Wre  = (float*)carve(24 * 8 * 9 * sizeof(float));
    float*    CPAD = (float*)carve((size_t)BB * CIMG * sizeof(float));
    float*    F0   = (float*)carve((size_t)BB * PIMG * sizeof(float));
    float*    F1   = (float*)carve((size_t)BB * PIMG * sizeof(float));
    unsigned* Wt   = (unsigned*)carve((size_t)13 * NPIX * sizeof(unsigned));
    OvfEntry* OVF  = (OvfEntry*)carve((size_t)OVF_CAP * sizeof(OvfEntry));
    int*      CNT  = (int*)carve(sizeof(int));
    (void)ws_size; (void)in_sizes; (void)n_in; (void)out_size;

    hipMemsetAsync(CNT, 0, sizeof(int), stream);

    int gridc = (BB * CIMG + 255) / 256;
    hipLaunchKernelGGL(k_permute, dim3(1), dim3(256), 0, stream, W_oa, Wre);
    hipLaunchKernelGGL(k_padconf, dim3(gridc), dim3(256), 0, stream,
                       confidence, CPAD);
    hipLaunchKernelGGL(k_precompute, dim3(GRID_PRE), dim3(256), 0, stream,
                       guidance, CPAD, feat_init, feat_fix, Wre, b_oa,
                       aff_scale, F0, F1, Wt, OVF, CNT);

    float* bufs[2] = {F0, F1};
    int cur = 0;
    for (int it = 0; it < 9; ++it) {
        int last = (it == 8) ? 1 : 0;
        float* outp = last ? (float*)d_out : bufs[cur ^ 1];
        hipLaunchKernelGGL(k_prop2, dim3(NTILES + 1), dim3(256), 0, stream,
                           bufs[cur], Wt, feat_fix, OVF, CNT, outp, last);
        cur ^= 1;
    }
}

// Round 10
// 418.715 us; speedup vs baseline: 2.8793x; 1.0427x over previous
//
#include <hip/hip_runtime.h>
#include <hip/hip_fp16.h>

#define BB 4
#define HH 240
#define WW 1216
#define NIMG (HH * WW)
#define NPIX (BB * NIMG)          // 1,167,360

// padded feat layout: image pixel (y,x) lives at (y+2, x+2); 5x5 window of
// pixel (y,x) starts at padded (y, x). Pad cells only ever get weight 0.
#define HHP (HH + 4)              // 244
#define WWP (WW + 4)              // 1220
#define PIMG (HHP * WWP)

// confidence padded with 2 zero rows/cols each side (+1 slack bottom/right)
#define CHP 245
#define CWP 1221
#define CIMG (CHP * CWP)

#define OVF_CAP 32768

// precompute tiling: 64x4 pixels per 256-thread block, guidance in LDS
#define PTW 64
#define PTH 4
#define PNBX (WW / PTW)           // 19
#define PNBY (HH / PTH)           // 60
#define GRID_PRE (PNBX * PNBY * BB)  // 4560
#define SGW 72                    // staged cols: tx0-1 .. tx0+70
#define SGH 6                     // staged rows: ty0-1 .. ty0+4
#define SGCH (SGH * SGW)          // 432 floats per channel

// fused 2-step tiling: B tile 64x16 (256 interior quads), 384-thread blocks
#define TSX 64
#define TSY 16
#define NTX (WW / TSX)            // 19
#define NTY (HH / TSY)            // 15
#define NTILES (NTX * NTY * BB)   // 1140
#define ARY 20                    // A rows (y: tiley-2 .. tiley+17)
#define ASTR 74                   // LDS row stride (74 mod 32 = 10: no repeat)

typedef __attribute__((ext_vector_type(2))) float float2v;

struct OvfEntry {                 // exception pixel: full 9-tap data
    int p;
    int base[9];                  // padded-layout corner base indices
    float w[36];                  // 4 premultiplied fp32 weights per tap
};

__device__ __forceinline__ unsigned f2h(float f) {
    union { _Float16 h; unsigned short u; } cv;
    cv.h = (_Float16)f;
    return (unsigned)cv.u;
}
__device__ __forceinline__ float h2f(unsigned u) {
    union { unsigned short u; _Float16 h; } cv;
    cv.u = (unsigned short)(u & 0xffffu);
    return (float)cv.h;
}

// ---------------------------------------------------------------------------
__global__ __launch_bounds__(256) void k_permute(const float* __restrict__ W_oa,
                                                 float* __restrict__ Wre) {
    for (int i = threadIdx.x; i < 24 * 8 * 9; i += 256) {
        int o = i / 72;
        int r = i - o * 72;
        int c = r / 9;
        int t = r - c * 9;
        Wre[(c * 9 + t) * 24 + o] = W_oa[i];
    }
}

__global__ __launch_bounds__(256) void k_padconf(const float* __restrict__ conf,
                                                 float* __restrict__ cpad) {
    int i = blockIdx.x * 256 + threadIdx.x;
    if (i >= BB * CIMG) return;
    int xp = i % CWP;
    int yp = (i / CWP) % CHP;
    int b = i / CIMG;
    float v = 0.f;
    int y = yp - 2, x = xp - 2;
    if (y >= 0 && y < HH && x >= 0 && x < WW) v = conf[b * NIMG + y * WW + x];
    cpad[i] = v;
}

__device__ __forceinline__ float fast_tanh(float x) {
    float xc = fminf(fmaxf(x, -15.f), 15.f);
    float e = __expf(2.f * xc);
    return 1.f - 2.f * __builtin_amdgcn_rcpf(e + 1.f);
}

// ---------------------------------------------------------------------------
// Precompute: guidance tile staged in LDS -> conv head -> affinities ->
// dense 5x5 window weights in registers. Wt PLANAR (coalesced). Flag plane
// 12 high half: bit15 = fixed pixel, bits[14:0] = ovf idx + 1.
// Fixed pixels pre-written into BOTH ping-pong buffers.
// ---------------------------------------------------------------------------
__global__ __launch_bounds__(256) void k_precompute(
    const float* __restrict__ guid, const float* __restrict__ cpad,
    const float* __restrict__ feat_init, const float* __restrict__ feat_fix,
    const float* __restrict__ Wre, const float* __restrict__ b_oa,
    const float* __restrict__ aff_scale,
    float* __restrict__ F0, float* __restrict__ F1,
    unsigned* __restrict__ Wt,
    OvfEntry* __restrict__ ovf, int* __restrict__ ovf_cnt) {
    __shared__ float sg[8 * SGCH];          // 13.8 KB
    const int tid = threadIdx.x;
    const int blk = blockIdx.x;
    const int b = blk / (PNBX * PNBY);
    const int tr = blk - b * (PNBX * PNBY);
    const int ty0 = (tr / PNBX) * PTH;
    const int tx0 = (tr - (tr / PNBX) * PNBX) * PTW;

    // ---- stage guidance 8ch x 6rows x 72cols (zero-padded borders) ----
    const float* gb = guid + (size_t)b * 8 * NIMG;
#pragma unroll 1
    for (int i = tid; i < 8 * SGCH; i += 256) {
        int c = i / SGCH;
        int rem = i - c * SGCH;
        int r = rem / SGW;
        int col = rem - r * SGW;
        int gy = ty0 - 1 + r;
        int gx = tx0 - 1 + col;
        float v = 0.f;
        if (gy >= 0 && gy < HH && gx >= 0 && gx < WW)
            v = gb[c * NIMG + gy * WW + gx];
        sg[i] = v;
    }
    __syncthreads();

    const int tx = tid & 63;
    const int ty = tid >> 6;
    const int x = tx0 + tx;
    const int y = ty0 + ty;
    const int p = b * NIMG + y * WW + x;

    float ff = feat_fix[p];
    bool isfix = (ff > 0.f);
    unsigned fixbit = isfix ? 0x8000u : 0u;

    // ---- 3x3 conv, 8 in-ch -> 24 out-ch from LDS (packed f32) ----
    float2v acc2[12];
    const float2v* b2 = (const float2v*)b_oa;
#pragma unroll
    for (int o = 0; o < 12; o++) acc2[o] = b2[o];

#pragma unroll 2
    for (int c = 0; c < 8; c++) {
        const float* sc = sg + c * SGCH + ty * SGW + tx;
        float gv[9];
#pragma unroll
        for (int t = 0; t < 9; t++)
            gv[t] = sc[(t / 3) * SGW + (t - (t / 3) * 3)];
#pragma unroll
        for (int t = 0; t < 9; t++) {
            const float2v* w2 = (const float2v*)(Wre + (c * 9 + t) * 24);
            float2v g2 = {gv[t], gv[t]};
#pragma unroll
            for (int o = 0; o < 12; o++)
                acc2[o] = __builtin_elementwise_fma(g2, w2[o], acc2[o]);
        }
    }

    float acc[24];
#pragma unroll
    for (int o = 0; o < 24; o++)
        acc[o] = (o & 1) ? acc2[o >> 1].y : acc2[o >> 1].x;

    // ---- TGASS affinity + confidence modulation ----
    float inv_ascale = __builtin_amdgcn_rcpf(aff_scale[0] + 1e-8f);
    const float* cb = cpad + (size_t)b * CIMG;
    float aff[8], ofy[8], ofx[8];
    float asum = 0.f;
#pragma unroll
    for (int k = 0; k < 8; k++) {
        float dy = acc[k];
        float dx = acc[8 + k];
        ofy[k] = dy;
        ofx[k] = dx;
        float a = fast_tanh(acc[16 + k]) * inv_ascale;
        float ys = dy + (float)y;
        float xs = dx + (float)x;
        float y0f = floorf(ys), x0f = floorf(xs);
        float wy = ys - y0f, wx = xs - x0f;
        int ya = (int)(fminf(fmaxf(y0f, -2.f), 241.f)) + 2;
        int yb = (int)(fminf(fmaxf(y0f + 1.f, -2.f), 241.f)) + 2;
        int xa = (int)(fminf(fmaxf(x0f, -2.f), 1217.f)) + 2;
        int xb = (int)(fminf(fmaxf(x0f + 1.f, -2.f), 1217.f)) + 2;
        float v00 = cb[ya * CWP + xa];
        float v01 = cb[ya * CWP + xb];
        float v10 = cb[yb * CWP + xa];
        float v11 = cb[yb * CWP + xb];
        float v = (v00 * (1.f - wx) + v01 * wx) * (1.f - wy)
                + (v10 * (1.f - wx) + v11 * wx) * wy;
        a *= v;
        aff[k] = a;
        asum += fabsf(a);
    }

    float s = fmaxf(asum + 1e-4f, 1.0f);
    float inv = __builtin_amdgcn_rcpf(s);
    float tot = 0.f;
#pragma unroll
    for (int k = 0; k < 8; k++) {
        aff[k] *= inv;
        tot += aff[k];
    }
    float aref = 1.0f - tot;

    // ---- register 5x5 window: separable outer-product accumulation ----
    float w[25];
#pragma unroll
    for (int i = 0; i < 25; i++) w[i] = 0.f;
    bool fits = true;
#pragma unroll
    for (int kk = 0; kk < 9; kk++) {
        float a, dy, dx;
        if (kk < 4)       { a = aff[kk];     dy = ofy[kk];     dx = ofx[kk]; }
        else if (kk == 4) { a = aref;        dy = 0.f;         dx = 0.f; }
        else              { a = aff[kk - 1]; dy = ofy[kk - 1]; dx = ofx[kk - 1]; }
        const int kh = kk / 3 - 1;
        const int kw = kk - (kk / 3) * 3 - 1;
        float fly = floorf(dy), flx = floorf(dx);
        fits = fits && (fly >= -1.f) && (fly <= 0.f)
                    && (flx >= -1.f) && (flx <= 0.f);
        float wy = dy - fly, wx = dx - flx;
        float byf = fly + 1.f, bxf = flx + 1.f;     // in {0,1} on fast path
        int y0 = y + kh + (int)fly;
        int x0 = x + kw + (int)flx;
        float cy0 = (y0 >= 0 && y0 <= HH - 1) ? (1.f - wy) : 0.f;
        float cy1 = (y0 + 1 >= 0 && y0 + 1 <= HH - 1) ? wy : 0.f;
        float cx0 = (x0 >= 0 && x0 <= WW - 1) ? (1.f - wx) : 0.f;
        float cx1 = (x0 + 1 >= 0 && x0 + 1 <= WW - 1) ? wx : 0.f;
        float cya0 = cy0 * a, cya1 = cy1 * a;
        float ry0 = cya0 - byf * cya0;
        float ry1 = fmaf(byf, cya0, cya1 - byf * cya1);
        float ry2 = byf * cya1;
        float rx0 = cx0 - bxf * cx0;
        float rx1 = fmaf(bxf, cx0, cx1 - bxf * cx1);
        float rx2 = bxf * cx1;
        const int base = (kh + 1) * 5 + (kw + 1);   // compile-time
        w[base + 0]  = fmaf(ry0, rx0, w[base + 0]);
        w[base + 1]  = fmaf(ry0, rx1, w[base + 1]);
        w[base + 2]  = fmaf(ry0, rx2, w[base + 2]);
        w[base + 5]  = fmaf(ry1, rx0, w[base + 5]);
        w[base + 6]  = fmaf(ry1, rx1, w[base + 6]);
        w[base + 7]  = fmaf(ry1, rx2, w[base + 7]);
        w[base + 10] = fmaf(ry2, rx0, w[base + 10]);
        w[base + 11] = fmaf(ry2, rx1, w[base + 11]);
        w[base + 12] = fmaf(ry2, rx2, w[base + 12]);
    }

    float yf = (float)y, xf = (float)x;
    if (fits) {
#pragma unroll
        for (int j = 0; j < 13; j++) {
            unsigned lo = f2h(w[2 * j]);
            unsigned hi = (j < 12) ? f2h(w[2 * j + 1]) : fixbit;
            Wt[(size_t)j * NPIX + p] = lo | (hi << 16);
        }
    } else {
        int slot = atomicAdd(ovf_cnt, 1);
        unsigned fl = (slot < OVF_CAP) ? (unsigned)(slot + 1) : 0x7fffu;
        if (slot < OVF_CAP) {
            OvfEntry* e = &ovf[slot];
            e->p = p;
#pragma unroll
            for (int kk = 0; kk < 9; kk++) {
                float a, dy, dx;
                if (kk < 4)       { a = aff[kk];     dy = ofy[kk];     dx = ofx[kk]; }
                else if (kk == 4) { a = aref;        dy = 0.f;         dx = 0.f; }
                else              { a = aff[kk - 1]; dy = ofy[kk - 1]; dx = ofx[kk - 1]; }
                float ys = yf + (float)(kk / 3 - 1) + dy;
                float xs = xf + (float)(kk - (kk / 3) * 3 - 1) + dx;
                float y0f = floorf(ys), x0f = floorf(xs);
                float wy = ys - y0f, wx = xs - x0f;
                float y0c = fminf(fmaxf(y0f, -2.f), (float)HH);
                float x0c = fminf(fmaxf(x0f, -2.f), (float)WW);
                int y0 = (int)y0c, x0 = (int)x0c;
                int by = min(max(y0, 0), HH - 2);
                int bx = min(max(x0, 0), WW - 2);
                float cy0 = 0.f, cy1 = 0.f;
                if (y0 >= 0 && y0 <= HH - 1) { if (y0 == by) cy0 = 1.f - wy; else cy1 = 1.f - wy; }
                if (y0 + 1 >= 0 && y0 + 1 <= HH - 1) { if (y0 + 1 == by) cy0 = wy; else cy1 = wy; }
                float cx0 = 0.f, cx1 = 0.f;
                if (x0 >= 0 && x0 <= WW - 1) { if (x0 == bx) cx0 = 1.f - wx; else cx1 = 1.f - wx; }
                if (x0 + 1 >= 0 && x0 + 1 <= WW - 1) { if (x0 + 1 == bx) cx0 = wx; else cx1 = wx; }
                e->base[kk] = (b * HHP + by + 2) * WWP + bx + 2;
                e->w[kk * 4 + 0] = cy0 * cx0 * a;
                e->w[kk * 4 + 1] = cy0 * cx1 * a;
                e->w[kk * 4 + 2] = cy1 * cx0 * a;
                e->w[kk * 4 + 3] = cy1 * cx1 * a;
            }
        }
#pragma unroll
        for (int j = 0; j < 13; j++)
            Wt[(size_t)j * NPIX + p] = (j == 12) ? ((fl | fixbit) << 16) : 0u;
    }

    // ---- initial feat (padded layout); fixed px into BOTH buffers ----
    int pp = (b * HHP + y + 2) * WWP + x + 2;
    F0[pp] = isfix ? ff : feat_init[p];
    if (isfix) F1[pp] = ff;
}

// general 9-tap (exception) raw stencil value from padded Fin
__device__ __forceinline__ float general9(const OvfEntry* __restrict__ e,
                                          const float* __restrict__ Fin) {
    float s = 0.f;
#pragma unroll
    for (int kk = 0; kk < 9; kk++) {
        int base = e->base[kk];
        s = fmaf(Fin[base],           e->w[kk * 4 + 0], s);
        s = fmaf(Fin[base + 1],       e->w[kk * 4 + 1], s);
        s = fmaf(Fin[base + WWP],     e->w[kk * 4 + 2], s);
        s = fmaf(Fin[base + WWP + 1], e->w[kk * 4 + 3], s);
    }
    return s;
}

// step-A mixed value of the pixel at padded index q (general, exception path)
__device__ float stepA_at(int q, const float* __restrict__ Fin,
                          const unsigned* __restrict__ Wt,
                          const float* __restrict__ feat_fix,
                          const OvfEntry* __restrict__ ovf) {
    int bq = q / PIMG;
    int rem = q - bq * PIMG;
    int yq = rem / WWP - 2;
    int xq = rem % WWP - 2;
    int pq = bq * NIMG + yq * WW + xq;
    float ff = feat_fix[pq];
    if (ff > 0.f) return ff;
    unsigned fl = (Wt[(size_t)12 * NPIX + pq] >> 16) & 0x7fffu;
    if (fl) return general9(&ovf[fl - 1], Fin);
    unsigned u13[13];
#pragma unroll
    for (int j = 0; j < 13; j++) u13[j] = Wt[(size_t)j * NPIX + pq];
    const float* fb = Fin + (q - 2 * WWP - 2);
    float s = 0.f;
#pragma unroll
    for (int c = 0; c < 25; c++) {
        const int j = c >> 1, r = c / 5, cc = c - r * 5;
        unsigned uw = (c & 1) ? (u13[j] >> 16) : u13[j];
        s = fmaf(fb[r * WWP + cc], h2f(uw), s);
    }
    return s;
}

// A-step for one quad (y, xq..xq+3): raw 5x5 stencil + ovf/fix overrides.
// Exports the quad's 13 packed weight words (kept for the B step).
__device__ __forceinline__ void quadA(
    int b, int y, int xq, bool valid,
    const float* __restrict__ Fin, const unsigned* __restrict__ Wt,
    const OvfEntry* __restrict__ ovf,
    uint4* __restrict__ u, float& s0, float& s1, float& s2, float& s3) {
    s0 = s1 = s2 = s3 = 0.f;
    if (!valid) return;
    int p = b * NIMG + y * WW + xq;
#pragma unroll
    for (int j = 0; j < 13; j++)
        u[j] = *(const uint4*)&Wt[(size_t)j * NPIX + p];
    const float* fb = Fin + (size_t)(b * HHP + y) * WWP + xq;
    float f[5][8];
#pragma unroll
    for (int r = 0; r < 5; r++) {
        const float* row = fb + r * WWP;
        float4 a0 = *(const float4*)(row);
        float4 a1 = *(const float4*)(row + 4);
        f[r][0] = a0.x; f[r][1] = a0.y; f[r][2] = a0.z; f[r][3] = a0.w;
        f[r][4] = a1.x; f[r][5] = a1.y; f[r][6] = a1.z; f[r][7] = a1.w;
    }
#pragma unroll
    for (int c = 0; c < 25; c++) {
        const int j = c >> 1, r = c / 5, cc = c - r * 5;
        unsigned e0 = (c & 1) ? (u[j].x >> 16) : u[j].x;
        unsigned e1 = (c & 1) ? (u[j].y >> 16) : u[j].y;
        unsigned e2 = (c & 1) ? (u[j].z >> 16) : u[j].z;
        unsigned e3 = (c & 1) ? (u[j].w >> 16) : u[j].w;
        s0 = fmaf(f[r][cc],     h2f(e0), s0);
        s1 = fmaf(f[r][cc + 1], h2f(e1), s1);
        s2 = fmaf(f[r][cc + 2], h2f(e2), s2);
        s3 = fmaf(f[r][cc + 3], h2f(e3), s3);
    }
    unsigned h0 = u[12].x >> 16, h1 = u[12].y >> 16;
    unsigned h2 = u[12].z >> 16, h3 = u[12].w >> 16;
    if ((h0 | h1 | h2 | h3) != 0) {         // rare: ovf / fixed overrides
        if (h0 & 0x7fffu) s0 = general9(&ovf[(h0 & 0x7fffu) - 1], Fin);
        if (h1 & 0x7fffu) s1 = general9(&ovf[(h1 & 0x7fffu) - 1], Fin);
        if (h2 & 0x7fffu) s2 = general9(&ovf[(h2 & 0x7fffu) - 1], Fin);
        if (h3 & 0x7fffu) s3 = general9(&ovf[(h3 & 0x7fffu) - 1], Fin);
        if (h0 & 0x8000u) s0 = fb[2 * WWP + 2];   // fixed: Fin value == ff
        if (h1 & 0x8000u) s1 = fb[2 * WWP + 3];
        if (h2 & 0x8000u) s2 = fb[2 * WWP + 4];
        if (h3 & 0x8000u) s3 = fb[2 * WWP + 5];
    }
}

// ---------------------------------------------------------------------------
// Fused 2-step propagation, 384-thread blocks (wave-balanced):
// threads 0-255 do their OWN interior quadA (weights kept in registers for
// the B step); threads 256-359 each do ONE halo quadA. A-phase critical
// path = 1 quadA for every wave. Barrier, then threads 0-255 compute B
// from LDS A-values + register weights (zero table re-reads).
// ---------------------------------------------------------------------------
__global__ __launch_bounds__(384) void k_prop2(
    const float* __restrict__ Fin, const unsigned* __restrict__ Wt,
    const float* __restrict__ feat_fix, const OvfEntry* __restrict__ ovf,
    const int* __restrict__ ovf_cnt, float* __restrict__ Fout, int last) {
    __shared__ float As[ARY * ASTR];
    const int tid = threadIdx.x;
    const int blk = blockIdx.x;

    if (blk == NTILES) {
        // -------- exception pixels: general 2-step from global Fin --------
        int cnt = *ovf_cnt;
        if (cnt > OVF_CAP) cnt = OVF_CAP;
        for (int i = tid; i < cnt; i += 384) {
            const OvfEntry* e = &ovf[i];
            float sB = 0.f;
#pragma unroll 1
            for (int kk = 0; kk < 9; kk++) {
                int base = e->base[kk];
                sB = fmaf(stepA_at(base,           Fin, Wt, feat_fix, ovf), e->w[kk * 4 + 0], sB);
                sB = fmaf(stepA_at(base + 1,       Fin, Wt, feat_fix, ovf), e->w[kk * 4 + 1], sB);
                sB = fmaf(stepA_at(base + WWP,     Fin, Wt, feat_fix, ovf), e->w[kk * 4 + 2], sB);
                sB = fmaf(stepA_at(base + WWP + 1, Fin, Wt, feat_fix, ovf), e->w[kk * 4 + 3], sB);
            }
            int p = e->p;
            if (last) {
                Fout[p] = sB;
            } else {
                float ff = feat_fix[p];
                int xx = p % WW;
                int yy = (p / WW) % HH;
                int bb = p / NIMG;
                Fout[(bb * HHP + yy + 2) * WWP + xx + 2] = (ff > 0.f) ? ff : sB;
            }
        }
        return;
    }

    const int b = blk / (NTX * NTY);
    const int tr = blk - b * (NTX * NTY);
    const int tiley = (tr / NTX) * TSY;
    const int tilex = (tr - (tr / NTX) * NTX) * TSX;
    const int qy = tid >> 4;                // interior decode (tid<256)
    const int qxl = tid & 15;

    uint4 u[13];
    float a0, a1, a2, a3;
    if (tid < 256) {
        // ---- A own interior quad (keep weights u for step B) ----
        quadA(b, tiley + qy, tilex + qxl * 4, true, Fin, Wt, ovf,
              u, a0, a1, a2, a3);
        float* ap = As + (qy + 2) * ASTR + (qxl + 1) * 4;
        float2v v01 = {a0, a1};
        float2v v23 = {a2, a3};
        *(float2v*)(ap) = v01;
        *(float2v*)(ap + 2) = v23;
    } else if (tid < 360) {
        // ---- A halo quad (rows 0,1,18,19 full; rows 2..17 cols 0,17) ----
        int h = tid - 256;
        int ar, ac;
        if (h < 36)      { ar = h / 18;             ac = h % 18; }
        else if (h < 72) { ar = 18 + (h - 36) / 18; ac = (h - 36) % 18; }
        else             { int i2 = h - 72; ar = 2 + (i2 >> 1); ac = (i2 & 1) * 17; }
        int ya = tiley - 2 + ar;
        int xa = tilex - 4 + ac * 4;
        bool valid = (ya >= 0) && (ya < HH) && (xa >= 0) && (xa < WW);
        quadA(b, ya, xa, valid, Fin, Wt, ovf, u, a0, a1, a2, a3);
        float* ap = As + ar * ASTR + ac * 4;
        float2v v01 = {a0, a1};
        float2v v23 = {a2, a3};
        *(float2v*)(ap) = v01;
        *(float2v*)(ap + 2) = v23;
    }
    __syncthreads();

    if (tid >= 256) return;

    // ---- B step: window from LDS, weights from kept registers ----
    float f[5][8];
    const float* As0 = As + qy * ASTR + qxl * 4 + 2;
#pragma unroll
    for (int r = 0; r < 5; r++) {
        const float* row = As0 + r * ASTR;
        float2v c0 = *(const float2v*)(row);
        float2v c1 = *(const float2v*)(row + 2);
        float2v c2 = *(const float2v*)(row + 4);
        float2v c3 = *(const float2v*)(row + 6);
        f[r][0] = c0.x; f[r][1] = c0.y; f[r][2] = c1.x; f[r][3] = c1.y;
        f[r][4] = c2.x; f[r][5] = c2.y; f[r][6] = c3.x; f[r][7] = c3.y;
    }

    float s0 = 0.f, s1 = 0.f, s2 = 0.f, s3 = 0.f;
#pragma unroll
    for (int c = 0; c < 25; c++) {
        const int j = c >> 1, r = c / 5, cc = c - r * 5;
        unsigned e0 = (c & 1) ? (u[j].x >> 16) : u[j].x;
        unsigned e1 = (c & 1) ? (u[j].y >> 16) : u[j].y;
        unsigned e2 = (c & 1) ? (u[j].z >> 16) : u[j].z;
        unsigned e3 = (c & 1) ? (u[j].w >> 16) : u[j].w;
        s0 = fmaf(f[r][cc],     h2f(e0), s0);
        s1 = fmaf(f[r][cc + 1], h2f(e1), s1);
        s2 = fmaf(f[r][cc + 2], h2f(e2), s2);
        s3 = fmaf(f[r][cc + 3], h2f(e3), s3);
    }
    unsigned h0 = u[12].x >> 16, h1 = u[12].y >> 16;
    unsigned h2 = u[12].z >> 16, h3 = u[12].w >> 16;

    const int yb = tiley + qy;
    const int xb = tilex + qxl * 4;
    if (last) {
        // store raw everywhere except ovf pixels (exception block writes)
        int p = b * NIMG + yb * WW + xb;
        if (((h0 | h1 | h2 | h3) & 0x7fffu) == 0) {
            float4 o = {s0, s1, s2, s3};
            *(float4*)&Fout[p] = o;
        } else {
            if (!(h0 & 0x7fffu)) Fout[p] = s0;
            if (!(h1 & 0x7fffu)) Fout[p + 1] = s1;
            if (!(h2 & 0x7fffu)) Fout[p + 2] = s2;
            if (!(h3 & 0x7fffu)) Fout[p + 3] = s3;
        }
    } else {
        // skip stores at fixed (bit15, value pre-baked) and ovf pixels
        float* po = Fout + (size_t)(b * HHP + yb + 2) * WWP + xb + 2;
        if ((h0 | h1 | h2 | h3) == 0) {
            float2v w01 = {s0, s1};
            float2v w23 = {s2, s3};
            *(float2v*)(po) = w01;
            *(float2v*)(po + 2) = w23;
        } else {
            if (!h0) po[0] = s0;
            if (!h1) po[1] = s1;
            if (!h2) po[2] = s2;
            if (!h3) po[3] = s3;
        }
    }
}

extern "C" void kernel_launch(void* const* d_in, const int* in_sizes, int n_in,
                              void* d_out, int out_size, void* d_ws, size_t ws_size,
                              hipStream_t stream) {
    const float* feat_init  = (const float*)d_in[0];
    const float* guidance   = (const float*)d_in[1];
    const float* confidence = (const float*)d_in[2];
    const float* feat_fix   = (const float*)d_in[3];
    const float* W_oa       = (const float*)d_in[4];
    const float* b_oa       = (const float*)d_in[5];
    const float* aff_scale  = (const float*)d_in[6];

    char* ws = (char*)d_ws;
    size_t off = 0;
    auto carve = [&](size_t bytes) -> char* {
        char* ptr = ws + off;
        off += (bytes + 511) & ~(size_t)511;
        return ptr;
    };
    float*    Wre  = (float*)carve(24 * 8 * 9 * sizeof(float));
    float*    CPAD = (float*)carve((size_t)BB * CIMG * sizeof(float));
    float*    F0   = (float*)carve((size_t)BB * PIMG * sizeof(float));
    float*    F1   = (float*)carve((size_t)BB * PIMG * sizeof(float));
    unsigned* Wt   = (unsigned*)carve((size_t)13 * NPIX * sizeof(unsigned));
    OvfEntry* OVF  = (OvfEntry*)carve((size_t)OVF_CAP * sizeof(OvfEntry));
    int*      CNT  = (int*)carve(sizeof(int));
    (void)ws_size; (void)in_sizes; (void)n_in; (void)out_size;

    hipMemsetAsync(CNT, 0, sizeof(int), stream);

    int gridc = (BB * CIMG + 255) / 256;
    hipLaunchKernelGGL(k_permute, dim3(1), dim3(256), 0, stream, W_oa, Wre);
    hipLaunchKernelGGL(k_padconf, dim3(gridc), dim3(256), 0, stream,
                       confidence, CPAD);
    hipLaunchKernelGGL(k_precompute, dim3(GRID_PRE), dim3(256), 0, stream,
                       guidance, CPAD, feat_init, feat_fix, Wre, b_oa,
                       aff_scale, F0, F1, Wt, OVF, CNT);

    float* bufs[2] = {F0, F1};
    int cur = 0;
    for (int it = 0; it < 9; ++it) {
        int last = (it == 8) ? 1 : 0;
        float* outp = last ? (float*)d_out : bufs[cur ^ 1];
        hipLaunchKernelGGL(k_prop2, dim3(NTILES + 1), dim3(384), 0, stream,
                           bufs[cur], Wt, feat_fix, OVF, CNT, outp, last);
        cur ^= 1;
    }
}

// Round 11
// 346.865 us; speedup vs baseline: 3.4757x; 1.2071x over previous
//
#include <hip/hip_runtime.h>
#include <hip/hip_fp16.h>

#define BB 4
#define HH 240
#define WW 1216
#define NIMG (HH * WW)
#define NPIX (BB * NIMG)          // 1,167,360

// padded feat layout: image pixel (y,x) lives at (y+2, x+2); 5x5 window of
// pixel (y,x) starts at padded (y, x). Pad cells only ever get weight 0.
#define HHP (HH + 4)              // 244
#define WWP (WW + 4)              // 1220
#define PIMG (HHP * WWP)

// confidence padded with 2 zero rows/cols each side (+1 slack bottom/right)
#define CHP 245
#define CWP 1221
#define CIMG (CHP * CWP)

#define OVF_CAP 32768

// precompute tiling: 64x4 pixels per 256-thread block, guidance in LDS
#define PTW 64
#define PTH 4
#define PNBX (WW / PTW)           // 19
#define PNBY (HH / PTH)           // 60
#define GRID_PRE (PNBX * PNBY * BB)  // 4560
#define SGW 72                    // staged cols: tx0-1 .. tx0+70
#define SGH 6                     // staged rows: ty0-1 .. ty0+4
#define SGCH (SGH * SGW)          // 432 floats per channel

// fused 2-step tiling: B tile 64x16 (256 interior quads), 384-thread blocks
#define TSX 64
#define TSY 16
#define NTX (WW / TSX)            // 19
#define NTY (HH / TSY)            // 15
#define NTILES (NTX * NTY * BB)   // 1140
#define ARY 20                    // A rows (y: tiley-2 .. tiley+17)
#define ASTR 74                   // LDS row stride (74 mod 32 = 10: no repeat)

typedef __attribute__((ext_vector_type(2))) float float2v;
typedef __attribute__((ext_vector_type(4))) float float4v;

struct OvfEntry {                 // exception pixel: full 9-tap data
    int p;
    int base[9];                  // padded-layout corner base indices
    float w[36];                  // 4 premultiplied fp32 weights per tap
};

__device__ __forceinline__ unsigned f2h(float f) {
    union { _Float16 h; unsigned short u; } cv;
    cv.h = (_Float16)f;
    return (unsigned)cv.u;
}
__device__ __forceinline__ float h2f(unsigned u) {
    union { unsigned short u; _Float16 h; } cv;
    cv.u = (unsigned short)(u & 0xffffu);
    return (float)cv.h;
}

// ---------------------------------------------------------------------------
__global__ __launch_bounds__(256) void k_permute(const float* __restrict__ W_oa,
                                                 float* __restrict__ Wre) {
    for (int i = threadIdx.x; i < 24 * 8 * 9; i += 256) {
        int o = i / 72;
        int r = i - o * 72;
        int c = r / 9;
        int t = r - c * 9;
        Wre[(c * 9 + t) * 24 + o] = W_oa[i];
    }
}

__global__ __launch_bounds__(256) void k_padconf(const float* __restrict__ conf,
                                                 float* __restrict__ cpad) {
    int i = blockIdx.x * 256 + threadIdx.x;
    if (i >= BB * CIMG) return;
    int xp = i % CWP;
    int yp = (i / CWP) % CHP;
    int b = i / CIMG;
    float v = 0.f;
    int y = yp - 2, x = xp - 2;
    if (y >= 0 && y < HH && x >= 0 && x < WW) v = conf[b * NIMG + y * WW + x];
    cpad[i] = v;
}

__device__ __forceinline__ float fast_tanh(float x) {
    float xc = fminf(fmaxf(x, -15.f), 15.f);
    float e = __expf(2.f * xc);
    return 1.f - 2.f * __builtin_amdgcn_rcpf(e + 1.f);
}

// ---------------------------------------------------------------------------
// Precompute: guidance tile staged in LDS -> conv head (float4 weight loads,
// packed f32 fma) -> affinities -> dense 5x5 window weights in registers.
// Wt PLANAR (coalesced). Flag plane 12 high half: bit15 = fixed pixel,
// bits[14:0] = ovf idx + 1. Fixed pixels pre-written into BOTH buffers.
// ---------------------------------------------------------------------------
__global__ __launch_bounds__(256) void k_precompute(
    const float* __restrict__ guid, const float* __restrict__ cpad,
    const float* __restrict__ feat_init, const float* __restrict__ feat_fix,
    const float* __restrict__ Wre, const float* __restrict__ b_oa,
    const float* __restrict__ aff_scale,
    float* __restrict__ F0, float* __restrict__ F1,
    unsigned* __restrict__ Wt,
    OvfEntry* __restrict__ ovf, int* __restrict__ ovf_cnt) {
    __shared__ float sg[8 * SGCH];          // 13.8 KB
    const int tid = threadIdx.x;
    const int blk = blockIdx.x;
    const int b = blk / (PNBX * PNBY);
    const int tr = blk - b * (PNBX * PNBY);
    const int ty0 = (tr / PNBX) * PTH;
    const int tx0 = (tr - (tr / PNBX) * PNBX) * PTW;

    // ---- stage guidance 8ch x 6rows x 72cols (zero-padded borders) ----
    const float* gb = guid + (size_t)b * 8 * NIMG;
#pragma unroll 1
    for (int i = tid; i < 8 * SGCH; i += 256) {
        int c = i / SGCH;
        int rem = i - c * SGCH;
        int r = rem / SGW;
        int col = rem - r * SGW;
        int gy = ty0 - 1 + r;
        int gx = tx0 - 1 + col;
        float v = 0.f;
        if (gy >= 0 && gy < HH && gx >= 0 && gx < WW)
            v = gb[c * NIMG + gy * WW + gx];
        sg[i] = v;
    }
    __syncthreads();

    const int tx = tid & 63;
    const int ty = tid >> 6;
    const int x = tx0 + tx;
    const int y = ty0 + ty;
    const int p = b * NIMG + y * WW + x;

    float ff = feat_fix[p];
    bool isfix = (ff > 0.f);
    unsigned fixbit = isfix ? 0x8000u : 0u;

    // ---- 3x3 conv, 8 in-ch -> 24 out-ch from LDS (float4 weights) ----
    float4v acc4[6];
    const float4v* b4 = (const float4v*)b_oa;
#pragma unroll
    for (int o = 0; o < 6; o++) acc4[o] = b4[o];

#pragma unroll 2
    for (int c = 0; c < 8; c++) {
        const float* sc = sg + c * SGCH + ty * SGW + tx;
        float gv[9];
#pragma unroll
        for (int t = 0; t < 9; t++)
            gv[t] = sc[(t / 3) * SGW + (t - (t / 3) * 3)];
#pragma unroll
        for (int t = 0; t < 9; t++) {
            const float4v* w4 = (const float4v*)(Wre + (c * 9 + t) * 24);
            float4v g4 = {gv[t], gv[t], gv[t], gv[t]};
#pragma unroll
            for (int o = 0; o < 6; o++)
                acc4[o] = __builtin_elementwise_fma(g4, w4[o], acc4[o]);
        }
    }

    float acc[24];
#pragma unroll
    for (int o = 0; o < 24; o++)
        acc[o] = acc4[o >> 2][o & 3];

    // ---- TGASS affinity + confidence modulation ----
    float inv_ascale = __builtin_amdgcn_rcpf(aff_scale[0] + 1e-8f);
    const float* cb = cpad + (size_t)b * CIMG;
    float aff[8], ofy[8], ofx[8];
    float asum = 0.f;
#pragma unroll
    for (int k = 0; k < 8; k++) {
        float dy = acc[k];
        float dx = acc[8 + k];
        ofy[k] = dy;
        ofx[k] = dx;
        float a = fast_tanh(acc[16 + k]) * inv_ascale;
        float ys = dy + (float)y;
        float xs = dx + (float)x;
        float y0f = floorf(ys), x0f = floorf(xs);
        float wy = ys - y0f, wx = xs - x0f;
        int ya = (int)(fminf(fmaxf(y0f, -2.f), 241.f)) + 2;
        int yb = (int)(fminf(fmaxf(y0f + 1.f, -2.f), 241.f)) + 2;
        int xa = (int)(fminf(fmaxf(x0f, -2.f), 1217.f)) + 2;
        int xb = (int)(fminf(fmaxf(x0f + 1.f, -2.f), 1217.f)) + 2;
        float v00 = cb[ya * CWP + xa];
        float v01 = cb[ya * CWP + xb];
        float v10 = cb[yb * CWP + xa];
        float v11 = cb[yb * CWP + xb];
        float v = (v00 * (1.f - wx) + v01 * wx) * (1.f - wy)
                + (v10 * (1.f - wx) + v11 * wx) * wy;
        a *= v;
        aff[k] = a;
        asum += fabsf(a);
    }

    float s = fmaxf(asum + 1e-4f, 1.0f);
    float inv = __builtin_amdgcn_rcpf(s);
    float tot = 0.f;
#pragma unroll
    for (int k = 0; k < 8; k++) {
        aff[k] *= inv;
        tot += aff[k];
    }
    float aref = 1.0f - tot;

    // ---- register 5x5 window: separable outer-product accumulation ----
    float w[25];
#pragma unroll
    for (int i = 0; i < 25; i++) w[i] = 0.f;
    bool fits = true;
#pragma unroll
    for (int kk = 0; kk < 9; kk++) {
        float a, dy, dx;
        if (kk < 4)       { a = aff[kk];     dy = ofy[kk];     dx = ofx[kk]; }
        else if (kk == 4) { a = aref;        dy = 0.f;         dx = 0.f; }
        else              { a = aff[kk - 1]; dy = ofy[kk - 1]; dx = ofx[kk - 1]; }
        const int kh = kk / 3 - 1;
        const int kw = kk - (kk / 3) * 3 - 1;
        float fly = floorf(dy), flx = floorf(dx);
        fits = fits && (fly >= -1.f) && (fly <= 0.f)
                    && (flx >= -1.f) && (flx <= 0.f);
        float wy = dy - fly, wx = dx - flx;
        float byf = fly + 1.f, bxf = flx + 1.f;     // in {0,1} on fast path
        int y0 = y + kh + (int)fly;
        int x0 = x + kw + (int)flx;
        float cy0 = (y0 >= 0 && y0 <= HH - 1) ? (1.f - wy) : 0.f;
        float cy1 = (y0 + 1 >= 0 && y0 + 1 <= HH - 1) ? wy : 0.f;
        float cx0 = (x0 >= 0 && x0 <= WW - 1) ? (1.f - wx) : 0.f;
        float cx1 = (x0 + 1 >= 0 && x0 + 1 <= WW - 1) ? wx : 0.f;
        float cya0 = cy0 * a, cya1 = cy1 * a;
        float ry0 = cya0 - byf * cya0;
        float ry1 = fmaf(byf, cya0, cya1 - byf * cya1);
        float ry2 = byf * cya1;
        float rx0 = cx0 - bxf * cx0;
        float rx1 = fmaf(bxf, cx0, cx1 - bxf * cx1);
        float rx2 = bxf * cx1;
        const int base = (kh + 1) * 5 + (kw + 1);   // compile-time
        w[base + 0]  = fmaf(ry0, rx0, w[base + 0]);
        w[base + 1]  = fmaf(ry0, rx1, w[base + 1]);
        w[base + 2]  = fmaf(ry0, rx2, w[base + 2]);
        w[base + 5]  = fmaf(ry1, rx0, w[base + 5]);
        w[base + 6]  = fmaf(ry1, rx1, w[base + 6]);
        w[base + 7]  = fmaf(ry1, rx2, w[base + 7]);
        w[base + 10] = fmaf(ry2, rx0, w[base + 10]);
        w[base + 11] = fmaf(ry2, rx1, w[base + 11]);
        w[base + 12] = fmaf(ry2, rx2, w[base + 12]);
    }

    float yf = (float)y, xf = (float)x;
    if (fits) {
#pragma unroll
        for (int j = 0; j < 13; j++) {
            unsigned lo = f2h(w[2 * j]);
            unsigned hi = (j < 12) ? f2h(w[2 * j + 1]) : fixbit;
            Wt[(size_t)j * NPIX + p] = lo | (hi << 16);
        }
    } else {
        int slot = atomicAdd(ovf_cnt, 1);
        unsigned fl = (slot < OVF_CAP) ? (unsigned)(slot + 1) : 0x7fffu;
        if (slot < OVF_CAP) {
            OvfEntry* e = &ovf[slot];
            e->p = p;
#pragma unroll
            for (int kk = 0; kk < 9; kk++) {
                float a, dy, dx;
                if (kk < 4)       { a = aff[kk];     dy = ofy[kk];     dx = ofx[kk]; }
                else if (kk == 4) { a = aref;        dy = 0.f;         dx = 0.f; }
                else              { a = aff[kk - 1]; dy = ofy[kk - 1]; dx = ofx[kk - 1]; }
                float ys = yf + (float)(kk / 3 - 1) + dy;
                float xs = xf + (float)(kk - (kk / 3) * 3 - 1) + dx;
                float y0f = floorf(ys), x0f = floorf(xs);
                float wy = ys - y0f, wx = xs - x0f;
                float y0c = fminf(fmaxf(y0f, -2.f), (float)HH);
                float x0c = fminf(fmaxf(x0f, -2.f), (float)WW);
                int y0 = (int)y0c, x0 = (int)x0c;
                int by = min(max(y0, 0), HH - 2);
                int bx = min(max(x0, 0), WW - 2);
                float cy0 = 0.f, cy1 = 0.f;
                if (y0 >= 0 && y0 <= HH - 1) { if (y0 == by) cy0 = 1.f - wy; else cy1 = 1.f - wy; }
                if (y0 + 1 >= 0 && y0 + 1 <= HH - 1) { if (y0 + 1 == by) cy0 = wy; else cy1 = wy; }
                float cx0 = 0.f, cx1 = 0.f;
                if (x0 >= 0 && x0 <= WW - 1) { if (x0 == bx) cx0 = 1.f - wx; else cx1 = 1.f - wx; }
                if (x0 + 1 >= 0 && x0 + 1 <= WW - 1) { if (x0 + 1 == bx) cx0 = wx; else cx1 = wx; }
                e->base[kk] = (b * HHP + by + 2) * WWP + bx + 2;
                e->w[kk * 4 + 0] = cy0 * cx0 * a;
                e->w[kk * 4 + 1] = cy0 * cx1 * a;
                e->w[kk * 4 + 2] = cy1 * cx0 * a;
                e->w[kk * 4 + 3] = cy1 * cx1 * a;
            }
        }
#pragma unroll
        for (int j = 0; j < 13; j++)
            Wt[(size_t)j * NPIX + p] = (j == 12) ? ((fl | fixbit) << 16) : 0u;
    }

    // ---- initial feat (padded layout); fixed px into BOTH buffers ----
    int pp = (b * HHP + y + 2) * WWP + x + 2;
    F0[pp] = isfix ? ff : feat_init[p];
    if (isfix) F1[pp] = ff;
}

// general 9-tap (exception) raw stencil value from padded Fin
__device__ __forceinline__ float general9(const OvfEntry* __restrict__ e,
                                          const float* __restrict__ Fin) {
    float s = 0.f;
#pragma unroll
    for (int kk = 0; kk < 9; kk++) {
        int base = e->base[kk];
        s = fmaf(Fin[base],           e->w[kk * 4 + 0], s);
        s = fmaf(Fin[base + 1],       e->w[kk * 4 + 1], s);
        s = fmaf(Fin[base + WWP],     e->w[kk * 4 + 2], s);
        s = fmaf(Fin[base + WWP + 1], e->w[kk * 4 + 3], s);
    }
    return s;
}

// step-A mixed value of the pixel at padded index q (general, exception path)
__device__ float stepA_at(int q, const float* __restrict__ Fin,
                          const unsigned* __restrict__ Wt,
                          const float* __restrict__ feat_fix,
                          const OvfEntry* __restrict__ ovf) {
    int bq = q / PIMG;
    int rem = q - bq * PIMG;
    int yq = rem / WWP - 2;
    int xq = rem % WWP - 2;
    int pq = bq * NIMG + yq * WW + xq;
    float ff = feat_fix[pq];
    if (ff > 0.f) return ff;
    unsigned fl = (Wt[(size_t)12 * NPIX + pq] >> 16) & 0x7fffu;
    if (fl) return general9(&ovf[fl - 1], Fin);
    unsigned u13[13];
#pragma unroll
    for (int j = 0; j < 13; j++) u13[j] = Wt[(size_t)j * NPIX + pq];
    const float* fb = Fin + (q - 2 * WWP - 2);
    float s = 0.f;
#pragma unroll
    for (int c = 0; c < 25; c++) {
        const int j = c >> 1, r = c / 5, cc = c - r * 5;
        unsigned uw = (c & 1) ? (u13[j] >> 16) : u13[j];
        s = fmaf(fb[r * WWP + cc], h2f(uw), s);
    }
    return s;
}

// A-step for one quad (y, xq..xq+3): raw 5x5 stencil + ovf/fix overrides.
// Exports the quad's 13 packed weight words (kept for the B step).
__device__ __forceinline__ void quadA(
    int b, int y, int xq, bool valid,
    const float* __restrict__ Fin, const unsigned* __restrict__ Wt,
    const OvfEntry* __restrict__ ovf,
    uint4* __restrict__ u, float& s0, float& s1, float& s2, float& s3) {
    s0 = s1 = s2 = s3 = 0.f;
    if (!valid) return;
    int p = b * NIMG + y * WW + xq;
#pragma unroll
    for (int j = 0; j < 13; j++)
        u[j] = *(const uint4*)&Wt[(size_t)j * NPIX + p];
    const float* fb = Fin + (size_t)(b * HHP + y) * WWP + xq;
    float f[5][8];
#pragma unroll
    for (int r = 0; r < 5; r++) {
        const float* row = fb + r * WWP;
        float4 a0 = *(const float4*)(row);
        float4 a1 = *(const float4*)(row + 4);
        f[r][0] = a0.x; f[r][1] = a0.y; f[r][2] = a0.z; f[r][3] = a0.w;
        f[r][4] = a1.x; f[r][5] = a1.y; f[r][6] = a1.z; f[r][7] = a1.w;
    }
#pragma unroll
    for (int c = 0; c < 25; c++) {
        const int j = c >> 1, r = c / 5, cc = c - r * 5;
        unsigned e0 = (c & 1) ? (u[j].x >> 16) : u[j].x;
        unsigned e1 = (c & 1) ? (u[j].y >> 16) : u[j].y;
        unsigned e2 = (c & 1) ? (u[j].z >> 16) : u[j].z;
        unsigned e3 = (c & 1) ? (u[j].w >> 16) : u[j].w;
        s0 = fmaf(f[r][cc],     h2f(e0), s0);
        s1 = fmaf(f[r][cc + 1], h2f(e1), s1);
        s2 = fmaf(f[r][cc + 2], h2f(e2), s2);
        s3 = fmaf(f[r][cc + 3], h2f(e3), s3);
    }
    unsigned h0 = u[12].x >> 16, h1 = u[12].y >> 16;
    unsigned h2 = u[12].z >> 16, h3 = u[12].w >> 16;
    if ((h0 | h1 | h2 | h3) != 0) {         // rare: ovf / fixed overrides
        if (h0 & 0x7fffu) s0 = general9(&ovf[(h0 & 0x7fffu) - 1], Fin);
        if (h1 & 0x7fffu) s1 = general9(&ovf[(h1 & 0x7fffu) - 1], Fin);
        if (h2 & 0x7fffu) s2 = general9(&ovf[(h2 & 0x7fffu) - 1], Fin);
        if (h3 & 0x7fffu) s3 = general9(&ovf[(h3 & 0x7fffu) - 1], Fin);
        if (h0 & 0x8000u) s0 = fb[2 * WWP + 2];   // fixed: Fin value == ff
        if (h1 & 0x8000u) s1 = fb[2 * WWP + 3];
        if (h2 & 0x8000u) s2 = fb[2 * WWP + 4];
        if (h3 & 0x8000u) s3 = fb[2 * WWP + 5];
    }
}

// ---------------------------------------------------------------------------
// Fused 2-step propagation, 384-thread blocks, XCD-aware tile swizzle:
// consecutive dispatch slots on one XCD process x-adjacent tiles so halo
// table/feat reads hit that XCD's L2. threads 0-255: own interior quadA
// (weights kept in registers for B); threads 256-359: one halo quadA each.
// ---------------------------------------------------------------------------
__global__ __launch_bounds__(384) void k_prop2(
    const float* __restrict__ Fin, const unsigned* __restrict__ Wt,
    const float* __restrict__ feat_fix, const OvfEntry* __restrict__ ovf,
    const int* __restrict__ ovf_cnt, float* __restrict__ Fout, int last) {
    __shared__ float As[ARY * ASTR];
    const int tid = threadIdx.x;
    int blk = blockIdx.x;

    if (blk == NTILES) {
        // -------- exception pixels: general 2-step from global Fin --------
        int cnt = *ovf_cnt;
        if (cnt > OVF_CAP) cnt = OVF_CAP;
        for (int i = tid; i < cnt; i += 384) {
            const OvfEntry* e = &ovf[i];
            float sB = 0.f;
#pragma unroll 1
            for (int kk = 0; kk < 9; kk++) {
                int base = e->base[kk];
                sB = fmaf(stepA_at(base,           Fin, Wt, feat_fix, ovf), e->w[kk * 4 + 0], sB);
                sB = fmaf(stepA_at(base + 1,       Fin, Wt, feat_fix, ovf), e->w[kk * 4 + 1], sB);
                sB = fmaf(stepA_at(base + WWP,     Fin, Wt, feat_fix, ovf), e->w[kk * 4 + 2], sB);
                sB = fmaf(stepA_at(base + WWP + 1, Fin, Wt, feat_fix, ovf), e->w[kk * 4 + 3], sB);
            }
            int p = e->p;
            if (last) {
                Fout[p] = sB;
            } else {
                float ff = feat_fix[p];
                int xx = p % WW;
                int yy = (p / WW) % HH;
                int bb = p / NIMG;
                Fout[(bb * HHP + yy + 2) * WWP + xx + 2] = (ff > 0.f) ? ff : sB;
            }
        }
        return;
    }

    // ---- bijective XCD swizzle (m204): NTILES = 8*142 + 4 ----
    {
        int xcd = blk & 7;
        int idx = blk >> 3;
        const int q = NTILES / 8;           // 142
        const int r = NTILES % 8;           // 4
        blk = (xcd < r) ? (xcd * (q + 1) + idx)
                        : (r * (q + 1) + (xcd - r) * q + idx);
    }

    const int b = blk / (NTX * NTY);
    const int tr = blk - b * (NTX * NTY);
    const int tiley = (tr / NTX) * TSY;
    const int tilex = (tr - (tr / NTX) * NTX) * TSX;
    const int qy = tid >> 4;                // interior decode (tid<256)
    const int qxl = tid & 15;

    uint4 u[13];
    float a0, a1, a2, a3;
    if (tid < 256) {
        // ---- A own interior quad (keep weights u for step B) ----
        quadA(b, tiley + qy, tilex + qxl * 4, true, Fin, Wt, ovf,
              u, a0, a1, a2, a3);
        float* ap = As + (qy + 2) * ASTR + (qxl + 1) * 4;
        float2v v01 = {a0, a1};
        float2v v23 = {a2, a3};
        *(float2v*)(ap) = v01;
        *(float2v*)(ap + 2) = v23;
    } else if (tid < 360) {
        // ---- A halo quad (rows 0,1,18,19 full; rows 2..17 cols 0,17) ----
        int h = tid - 256;
        int ar, ac;
        if (h < 36)      { ar = h / 18;             ac = h % 18; }
        else if (h < 72) { ar = 18 + (h - 36) / 18; ac = (h - 36) % 18; }
        else             { int i2 = h - 72; ar = 2 + (i2 >> 1); ac = (i2 & 1) * 17; }
        int ya = tiley - 2 + ar;
        int xa = tilex - 4 + ac * 4;
        bool valid = (ya >= 0) && (ya < HH) && (xa >= 0) && (xa < WW);
        quadA(b, ya, xa, valid, Fin, Wt, ovf, u, a0, a1, a2, a3);
        float* ap = As + ar * ASTR + ac * 4;
        float2v v01 = {a0, a1};
        float2v v23 = {a2, a3};
        *(float2v*)(ap) = v01;
        *(float2v*)(ap + 2) = v23;
    }
    __syncthreads();

    if (tid >= 256) return;

    // ---- B step: window from LDS, weights from kept registers ----
    float f[5][8];
    const float* As0 = As + qy * ASTR + qxl * 4 + 2;
#pragma unroll
    for (int r = 0; r < 5; r++) {
        const float* row = As0 + r * ASTR;
        float2v c0 = *(const float2v*)(row);
        float2v c1 = *(const float2v*)(row + 2);
        float2v c2 = *(const float2v*)(row + 4);
        float2v c3 = *(const float2v*)(row + 6);
        f[r][0] = c0.x; f[r][1] = c0.y; f[r][2] = c1.x; f[r][3] = c1.y;
        f[r][4] = c2.x; f[r][5] = c2.y; f[r][6] = c3.x; f[r][7] = c3.y;
    }

    float s0 = 0.f, s1 = 0.f, s2 = 0.f, s3 = 0.f;
#pragma unroll
    for (int c = 0; c < 25; c++) {
        const int j = c >> 1, r = c / 5, cc = c - r * 5;
        unsigned e0 = (c & 1) ? (u[j].x >> 16) : u[j].x;
        unsigned e1 = (c & 1) ? (u[j].y >> 16) : u[j].y;
        unsigned e2 = (c & 1) ? (u[j].z >> 16) : u[j].z;
        unsigned e3 = (c & 1) ? (u[j].w >> 16) : u[j].w;
        s0 = fmaf(f[r][cc],     h2f(e0), s0);
        s1 = fmaf(f[r][cc + 1], h2f(e1), s1);
        s2 = fmaf(f[r][cc + 2], h2f(e2), s2);
        s3 = fmaf(f[r][cc + 3], h2f(e3), s3);
    }
    unsigned h0 = u[12].x >> 16, h1 = u[12].y >> 16;
    unsigned h2 = u[12].z >> 16, h3 = u[12].w >> 16;

    const int yb = tiley + qy;
    const int xb = tilex + qxl * 4;
    if (last) {
        // store raw everywhere except ovf pixels (exception block writes)
        int p = b * NIMG + yb * WW + xb;
        if (((h0 | h1 | h2 | h3) & 0x7fffu) == 0) {
            float4 o = {s0, s1, s2, s3};
            *(float4*)&Fout[p] = o;
        } else {
            if (!(h0 & 0x7fffu)) Fout[p] = s0;
            if (!(h1 & 0x7fffu)) Fout[p + 1] = s1;
            if (!(h2 & 0x7fffu)) Fout[p + 2] = s2;
            if (!(h3 & 0x7fffu)) Fout[p + 3] = s3;
        }
    } else {
        // skip stores at fixed (bit15, value pre-baked) and ovf pixels
        float* po = Fout + (size_t)(b * HHP + yb + 2) * WWP + xb + 2;
        if ((h0 | h1 | h2 | h3) == 0) {
            float2v w01 = {s0, s1};
            float2v w23 = {s2, s3};
            *(float2v*)(po) = w01;
            *(float2v*)(po + 2) = w23;
        } else {
            if (!h0) po[0] = s0;
            if (!h1) po[1] = s1;
            if (!h2) po[2] = s2;
            if (!h3) po[3] = s3;
        }
    }
}

extern "C" void kernel_launch(void* const* d_in, const int* in_sizes, int n_in,
                              void* d_out, int out_size, void* d_ws, size_t ws_size,
                              hipStream_t stream) {
    const float* feat_init  = (const float*)d_in[0];
    const float* guidance   = (const float*)d_in[1];
    const float* confidence = (const float*)d_in[2];
    const float* feat_fix   = (const float*)d_in[3];
    const float* W_oa       = (const float*)d_in[4];
    const float* b_oa       = (const float*)d_in[5];
    const float* aff_scale  = (const float*)d_in[6];

    char* ws = (char*)d_ws;
    size_t off = 0;
    auto carve = [&](size_t bytes) -> char* {
        char* ptr = ws + off;
        off += (bytes + 511) & ~(size_t)511;
        return ptr;
    };
    float*    Wre  = (float*)carve(24 * 8 * 9 * sizeof(float));
    float*    CPAD = (float*)carve((size_t)BB * CIMG * sizeof(float));
    float*    F0   = (float*)carve((size_t)BB * PIMG * sizeof(float));
    float*    F1   = (float*)carve((size_t)BB * PIMG * sizeof(float));
    unsigned* Wt   = (unsigned*)carve((size_t)13 * NPIX * sizeof(unsigned));
    OvfEntry* OVF  = (OvfEntry*)carve((size_t)OVF_CAP * sizeof(OvfEntry));
    int*      CNT  = (int*)carve(sizeof(int));
    (void)ws_size; (void)in_sizes; (void)n_in; (void)out_size;

    hipMemsetAsync(CNT, 0, sizeof(int), stream);

    int gridc = (BB * CIMG + 255) / 256;
    hipLaunchKernelGGL(k_permute, dim3(1), dim3(256), 0, stream, W_oa, Wre);
    hipLaunchKernelGGL(k_padconf, dim3(gridc), dim3(256), 0, stream,
                       confidence, CPAD);
    hipLaunchKernelGGL(k_precompute, dim3(GRID_PRE), dim3(256), 0, stream,
                       guidance, CPAD, feat_init, feat_fix, Wre, b_oa,
                       aff_scale, F0, F1, Wt, OVF, CNT);

    float* bufs[2] = {F0, F1};
    int cur = 0;
    for (int it = 0; it < 9; ++it) {
        int last = (it == 8) ? 1 : 0;
        float* outp = last ? (float*)d_out : bufs[cur ^ 1];
        hipLaunchKernelGGL(k_prop2, dim3(NTILES + 1), dim3(384), 0, stream,
                           bufs[cur], Wt, feat_fix, OVF, CNT, outp, last);
        cur ^= 1;
    }
}